// Round 10
// baseline (134.395 us; speedup 1.0000x reference)
//
#include <hip/hip_runtime.h>
#include <math.h>

#define HW    16384
#define WID   128
#define NB    4
// output section offsets (floats)
#define OFF_U 3932160
#define OFF_L 4259840
#define OFF_F 4456448

// fused conv tile geometry (ch-interleaved bf16)
#define TCH   24
#define TROW  132
#define TL_N  (6*TROW*TCH)    // main tile: 6 rows (y0-2..y0+3)        19008 sh
#define WG_N  (9*32*TCH)      // gates weights [9][32][24]              6912 sh
#define WC_N  (9*16*TCH)      // cand  weights [9][16][24]              3456 sh
#define RH_N  (4*TROW*12)     // rh tile [4 rows][132][12]              6336 sh
#define UL_N  (2*TROW*12)     // u  tile [2 rows][132][12]              3168 sh
// total 38880 shorts = 77.76 KB -> 2 blocks/CU

typedef __attribute__((ext_vector_type(8))) short  short8_t;
typedef __attribute__((ext_vector_type(4))) float  float4_t;

__device__ __forceinline__ float sig_(float x)  { return 1.f/(1.f+__expf(-x)); }
__device__ __forceinline__ float tanh_(float x) { float e=__expf(2.f*x); return 1.f - 2.f/(e+1.f); }
__device__ __forceinline__ unsigned short f2bf(float x){          // RNE fp32->bf16
  unsigned u = __float_as_uint(x);
  return (unsigned short)((u + 0x7fffu + ((u>>16)&1u)) >> 16);
}
__device__ __forceinline__ float bf2f(unsigned short s){
  unsigned u = ((unsigned)s) << 16;
  return __uint_as_float(u);
}

// ---------------------------------------------------------------------------
// Kernel A: node-split (grid 1536 = 6 nodes x 256 pixel-blocks)  [unchanged]
// ---------------------------------------------------------------------------
__global__ __launch_bounds__(256)
void k_att_dec(const float* __restrict__ hn, const float* __restrict__ pnn,
               const float* __restrict__ Wdau, const float* __restrict__ bdau,
               const float* __restrict__ Wdal, const float* __restrict__ bdal,
               const float* __restrict__ Wd1, const float* __restrict__ s1v, const float* __restrict__ t1v,
               const float* __restrict__ Wd2, const float* __restrict__ s2v, const float* __restrict__ t2v,
               const float* __restrict__ Wa0, const float* __restrict__ Wa1, const float* __restrict__ Wa2,
               const float* __restrict__ Wa3, const float* __restrict__ Wa4, const float* __restrict__ Wa5,
               const float* __restrict__ batt,
               float* __restrict__ out, float* __restrict__ wmsg)
{
  const int n   = blockIdx.x >> 8;
  const int g   = (blockIdx.x & 255)*256 + threadIdx.x;
  const int b   = g >> 14;
  const int pix = g & 16383;

  float h[10];
  float a;
  if (n < 4){
#pragma unroll
    for (int c=0;c<10;c++) h[c] = hn[(b*10+c)*HW + pix];
    float v[5]; float mx = -1e30f;
#pragma unroll
    for (int o=0;o<5;o++){
      float t = bdau[o];
#pragma unroll
      for (int c=0;c<10;c++) t += Wdau[o*10+c]*h[c];
      if (n==0) out[OFF_U + (b*5+o)*HW + pix] = t;
      v[o]=t; mx = fmaxf(mx,t);
    }
    float s=0.f;
#pragma unroll
    for (int o=0;o<5;o++){ v[o]=__expf(v[o]-mx); s+=v[o]; }
    a = v[n+1]/s;
  } else {
#pragma unroll
    for (int c=0;c<10;c++) h[c] = hn[((NB+b)*10+c)*HW + pix];
    float v[3]; float mx = -1e30f;
#pragma unroll
    for (int o=0;o<3;o++){
      float t = bdal[o];
#pragma unroll
      for (int c=0;c<10;c++) t += Wdal[o*10+c]*h[c];
      if (n==4) out[OFF_L + (b*3+o)*HW + pix] = t;
      v[o]=t; mx = fmaxf(mx,t);
    }
    float s=0.f;
#pragma unroll
    for (int o=0;o<3;o++){ v[o]=__expf(v[o]-mx); s+=v[o]; }
    a = v[n-3]/s;
  }

  float child[10];
#pragma unroll
  for (int c=0;c<10;c++) child[c] = pnn[((n*NB+b)*10+c)*HW + pix];

  float af = batt[n];
  if (n==0){
#pragma unroll
    for (int c=0;c<10;c++) af += Wa0[c]*pnn[((1*NB+b)*10+c)*HW+pix];
  } else if (n==1){
#pragma unroll
    for (int c=0;c<10;c++){
      af += Wa1[c]   *pnn[((0*NB+b)*10+c)*HW+pix];
      af += Wa1[10+c]*pnn[((2*NB+b)*10+c)*HW+pix];
      af += Wa1[20+c]*pnn[((3*NB+b)*10+c)*HW+pix];
      af += Wa1[30+c]*pnn[((4*NB+b)*10+c)*HW+pix];
    }
  } else if (n==2){
#pragma unroll
    for (int c=0;c<10;c++) af += Wa2[c]*pnn[((1*NB+b)*10+c)*HW+pix];
  } else if (n==3){
#pragma unroll
    for (int c=0;c<10;c++) af += Wa3[c]*pnn[((1*NB+b)*10+c)*HW+pix];
  } else if (n==4){
#pragma unroll
    for (int c=0;c<10;c++){
      af += Wa4[c]   *pnn[((1*NB+b)*10+c)*HW+pix];
      af += Wa4[10+c]*pnn[((5*NB+b)*10+c)*HW+pix];
    }
  } else {
#pragma unroll
    for (int c=0;c<10;c++) af += Wa5[c]*pnn[((4*NB+b)*10+c)*HW+pix];
  }
  out[OFF_F + (n*NB+b)*HW + pix] = sig_(af);

  float x20[20];
#pragma unroll
  for (int c=0;c<10;c++){ x20[c]=h[c]*a; x20[10+c]=child[c]; }
  float h20[20];
#pragma unroll
  for (int o=0;o<20;o++){
    float acc=0.f;
#pragma unroll
    for (int c=0;c<20;c++) acc += Wd1[o*20+c]*x20[c];
    h20[o] = fmaxf(acc*s1v[o]+t1v[o], 0.f);
  }
#pragma unroll
  for (int o=0;o<10;o++){
    float acc=0.f;
#pragma unroll
    for (int c=0;c<20;c++) acc += Wd2[o*20+c]*h20[c];
    wmsg[((n*NB+b)*10+o)*HW + pix] = fmaxf(acc*s2v[o]+t2v[o], 0.f);
  }
}

// ---------------------------------------------------------------------------
// Kernel B: projection GEMM v3 (unchanged from round 9)
// ---------------------------------------------------------------------------
__global__ __launch_bounds__(256, 2)
void k_proj(const float* __restrict__ xp, const float* __restrict__ Wp,
            const float* __restrict__ ps, const float* __restrict__ pt,
            const float* __restrict__ outf, float* __restrict__ wmsg)
{
  __shared__ __align__(16) unsigned short wlds[64*264];
  const int tid = threadIdx.x;

#pragma unroll
  for (int it=0; it<16; ++it){
    const int e = tid + it*256;
    const int row = e >> 6, q = e & 63;
    uint2 pk; pk.x = 0u; pk.y = 0u;
    if (row < 60){
      const float s = ps[row];
      float4 wv = *reinterpret_cast<const float4*>(Wp + row*256 + q*4);
      pk.x = (unsigned)f2bf(wv.x*s) | ((unsigned)f2bf(wv.y*s)<<16);
      pk.y = (unsigned)f2bf(wv.z*s) | ((unsigned)f2bf(wv.w*s)<<16);
    }
    *reinterpret_cast<uint2*>(&wlds[row*264 + q*4]) = pk;
  }
  __syncthreads();

  const int l  = tid & 63;
  const int w  = tid >> 6;
  const int lr = l & 15;
  const int lk = l >> 4;

  const int tile = blockIdx.x*4 + w;
  const int P    = tile*16;
  const int b    = P >> 14;
  const int pixb = P & 16383;
  const int px   = pixb + lr;

  const float* xb = xp + (size_t)(b*256)*HW + px;
  float v[64];
#pragma unroll
  for (int ks=0; ks<8; ++ks)
#pragma unroll
    for (int j=0; j<8; ++j)
      v[ks*8+j] = xb[(size_t)(ks*32 + lk*8 + j)*HW];

  short8_t bf[8];
#pragma unroll
  for (int ks=0; ks<8; ++ks)
#pragma unroll
    for (int j=0; j<8; ++j)
      bf[ks][j] = (short)f2bf(v[ks*8+j]);

  float4_t acc[4];
#pragma unroll
  for (int nf=0;nf<4;nf++){ acc[nf][0]=0.f; acc[nf][1]=0.f; acc[nf][2]=0.f; acc[nf][3]=0.f; }

#pragma unroll
  for (int ks=0; ks<8; ++ks){
#pragma unroll
    for (int nf=0; nf<4; ++nf){
      short8_t wa = *reinterpret_cast<const short8_t*>(&wlds[(nf*16+lr)*264 + ks*32 + lk*8]);
      acc[nf] = __builtin_amdgcn_mfma_f32_16x16x32_bf16(wa, bf[ks], acc[nf], 0,0,0);
    }
  }

#pragma unroll
  for (int nf=0;nf<4;nf++){
#pragma unroll
    for (int j=0;j<4;j++){
      const int row = nf*16 + lk*4 + j;
      if (row < 60){
        const unsigned nn = (unsigned)row / 10u;
        const int o = row - (int)nn*10;
        float att = outf[OFF_F + (nn*NB+b)*HW + pixb + lr];
        float val = fmaxf((2.f - att)*acc[nf][j] + pt[row], 0.f);
        size_t idx = ((size_t)((nn*NB+b)*10 + o))*HW + pixb + lr;
        wmsg[idx] += val;
      }
    }
  }
}

// ---------------------------------------------------------------------------
// Kernel C: FUSED ConvGRU (gates + candidate + blend), rh/u stay in LDS.
// Block = (n,b, 2-row out tile).  Stage 6 msg/pnn rows once.
// Phase 1: gates conv on 4 rows (y0-1..y0+2) -> rh (bf16 LDS), u (bf16 LDS).
// Phase 2: cand conv (k-map: slots 0..9 = msg, 12..21 = rh) + GRU blend -> out.
// ---------------------------------------------------------------------------
__global__ __launch_bounds__(256)
void k_gru_fused(const float* __restrict__ pnn, const float* __restrict__ Wg,
                 const float* __restrict__ bg, const float* __restrict__ Wc,
                 const float* __restrict__ bc,
                 const float* __restrict__ wmsg, float* __restrict__ out)
{
  __shared__ __align__(16) unsigned short tl [TL_N];
  __shared__ __align__(16) unsigned short wlg[WG_N];
  __shared__ __align__(16) unsigned short wlc[WC_N];
  __shared__ __align__(16) unsigned short rhl[RH_N];
  __shared__ __align__(16) unsigned short ul [UL_N];

  const int bi = blockIdx.x;
  const int n  = bi >> 8;
  const int b  = (bi >> 6) & 3;
  const int y0 = (bi & 63) * 2;
  const int tid = threadIdx.x;

  const int base_nb = (n*NB+b)*10;
  const float* msgb = wmsg + (size_t)base_nb*HW;
  const float* pb   = pnn  + (size_t)base_nb*HW;

  short8_t zz = {0,0,0,0,0,0,0,0};
  // zero all LDS buffers (halos, pads, skipped rows)
#pragma unroll
  for (int it=0; it<10; ++it){ int e = tid*8 + it*2048; if (e < TL_N) *reinterpret_cast<short8_t*>(&tl[e])  = zz; }
#pragma unroll
  for (int it=0; it<4;  ++it){ int e = tid*8 + it*2048; if (e < WG_N) *reinterpret_cast<short8_t*>(&wlg[e]) = zz; }
#pragma unroll
  for (int it=0; it<2;  ++it){ int e = tid*8 + it*2048; if (e < WC_N) *reinterpret_cast<short8_t*>(&wlc[e]) = zz; }
#pragma unroll
  for (int it=0; it<4;  ++it){ int e = tid*8 + it*2048; if (e < RH_N) *reinterpret_cast<short8_t*>(&rhl[e]) = zz; }
#pragma unroll
  for (int it=0; it<2;  ++it){ int e = tid*8 + it*2048; if (e < UL_N) *reinterpret_cast<short8_t*>(&ul[e])  = zz; }
  __syncthreads();

  // ---- stage gates weights [9][o:32][24] (k = ch 0..19) ----
  const float* Wgn = Wg + n*3600;
#pragma unroll
  for (int it=0; it<8; ++it){
    const int e = tid + it*256;
    if (e < 1800){
      int sh = e/200, rem = e - sh*200, o = rem/10, chp = rem - o*10;
      float w0 = Wgn[o*180 + (2*chp  )*9 + sh];
      float w1 = Wgn[o*180 + (2*chp+1)*9 + sh];
      unsigned pk = (unsigned)f2bf(w0) | ((unsigned)f2bf(w1)<<16);
      *reinterpret_cast<unsigned*>(&wlg[(sh*32+o)*TCH + 2*chp]) = pk;
    }
  }
  // ---- stage cand weights [9][o:16][24] (k: slot<10 = msg ch, slot 12..21 = rh ch) ----
  const float* Wcn = Wc + n*1800;
#pragma unroll
  for (int it=0; it<4; ++it){
    const int e = tid + it*256;
    if (e < 900){
      int sh = e/100, rem = e - sh*100, o = rem/10, chp = rem - o*10;
      float w0 = Wcn[o*180 + (2*chp  )*9 + sh];
      float w1 = Wcn[o*180 + (2*chp+1)*9 + sh];
      unsigned pk = (unsigned)f2bf(w0) | ((unsigned)f2bf(w1)<<16);
      const int slot = (chp < 5) ? 2*chp : 2*chp + 2;   // skip slots 10,11
      *reinterpret_cast<unsigned*>(&wlc[(sh*16+o)*TCH + slot]) = pk;
    }
  }
  // ---- stage main tile: 6 rows x 10 chp x 128  (msg ch 0..9, pnn ch 10..19) ----
#pragma unroll
  for (int it=0; it<30; ++it){
    const int e = tid + it*256;            // < 7680 always
    int row = e/1280, rem = e - row*1280, chp = rem>>7, x = rem&127;
    int yy = y0 - 2 + row;
    if ((unsigned)yy < 128u){
      const float* s0 = (chp<5) ? (msgb + (size_t)(2*chp)*HW) : (pb + (size_t)(2*chp-10)*HW);
      float v0 = s0[yy*WID + x];
      float v1 = s0[HW + yy*WID + x];
      unsigned pk = (unsigned)f2bf(v0) | ((unsigned)f2bf(v1)<<16);
      *reinterpret_cast<unsigned*>(&tl[(row*TROW + x+1)*TCH + 2*chp]) = pk;
    }
  }
  __syncthreads();

  const int l  = tid & 63;
  const int w  = tid >> 6;
  const int lr = l & 15;
  const int lk = l >> 4;

  // ===== phase 1: gates conv on 4 rows =====
  short8_t wa0[9], wa1[9];
#pragma unroll
  for (int sh=0; sh<9; sh++){
    wa0[sh] = (lk<3) ? *reinterpret_cast<const short8_t*>(&wlg[(sh*32 +      lr)*TCH + lk*8]) : zz;
    wa1[sh] = (lk<3) ? *reinterpret_cast<const short8_t*>(&wlg[(sh*32 + 16 + lr)*TCH + lk*8]) : zz;
  }
  float bs0[4], bs1[4];
#pragma unroll
  for (int j=0;j<4;j++){
    bs0[j] = bg[n*20 + lk*4 + j];
    int o1 = 16 + lk*4 + j;
    bs1[j] = (o1 < 20) ? bg[n*20 + o1] : 0.f;
  }

  for (int t=0; t<8; ++t){
    const int tg = w*8 + t;
    const int gy = tg >> 3;            // 0..3 -> global y = y0-1+gy
    const int xt = tg & 7;
    const int y  = y0 - 1 + gy;
    if ((unsigned)y > 127u) continue;

    float4_t a0 = {0.f,0.f,0.f,0.f}, a1 = {0.f,0.f,0.f,0.f};
#pragma unroll
    for (int sh=0; sh<9; sh++){
      const int dyr = sh/3, dx = sh - dyr*3;
      const int addr = ((gy+dyr)*TROW + (xt*16 + lr + dx))*TCH + lk*8;
      short8_t bfv = (lk<3) ? *reinterpret_cast<const short8_t*>(&tl[addr]) : zz;
      a0 = __builtin_amdgcn_mfma_f32_16x16x32_bf16(wa0[sh], bfv, a0, 0,0,0);
      a1 = __builtin_amdgcn_mfma_f32_16x16x32_bf16(wa1[sh], bfv, a1, 0,0,0);
    }

    const int px   = xt*16 + lr;
    const int ctr  = (gy+1)*TROW + px + 1;        // center cell in main tile
    const bool urow = (gy==1) || (gy==2);
#pragma unroll
    for (int jp=0; jp<2; ++jp){
      const int j0 = 2*jp;
      const int o  = lk*4 + j0;
      float g0 = sig_(a0[j0]   + bs0[j0]);
      float g1 = sig_(a0[j0+1] + bs0[j0+1]);
      if (o < 10){                                 // r-gate pair -> rh
        unsigned hp = *reinterpret_cast<const unsigned*>(&tl[ctr*TCH + 10 + o]);
        float h0 = bf2f((unsigned short)(hp & 0xffffu));
        float h1 = bf2f((unsigned short)(hp >> 16));
        unsigned pk = (unsigned)f2bf(g0*h0) | ((unsigned)f2bf(g1*h1) << 16);
        *reinterpret_cast<unsigned*>(&rhl[(gy*TROW + px + 1)*12 + o]) = pk;
      } else if (urow){                            // u pair (u ch 0..5)
        unsigned pk = (unsigned)f2bf(g0) | ((unsigned)f2bf(g1) << 16);
        *reinterpret_cast<unsigned*>(&ul[((gy-1)*TROW + px + 1)*12 + (o - 10)]) = pk;
      }
    }
    if (lk == 0 && urow){                          // a1 o1=16..19 -> u ch 6..9
#pragma unroll
      for (int jp=0; jp<2; ++jp){
        const int j0 = 2*jp;
        float g0 = sig_(a1[j0]   + bs1[j0]);
        float g1 = sig_(a1[j0+1] + bs1[j0+1]);
        unsigned pk = (unsigned)f2bf(g0) | ((unsigned)f2bf(g1) << 16);
        *reinterpret_cast<unsigned*>(&ul[((gy-1)*TROW + px + 1)*12 + 6 + j0]) = pk;
      }
    }
  }
  __syncthreads();

  // ===== phase 2: candidate conv + GRU blend =====
  short8_t wac[9];
#pragma unroll
  for (int sh=0; sh<9; sh++)
    wac[sh] = (lk<3) ? *reinterpret_cast<const short8_t*>(&wlc[(sh*16 + lr)*TCH + lk*8]) : zz;
  float bsc[4];
#pragma unroll
  for (int j=0;j<4;j++){
    int o = lk*4 + j;
    bsc[j] = (o < 10) ? bc[n*10 + o] : 0.f;
  }

  for (int t=0; t<4; ++t){
    const int ct = w*4 + t;
    const int cy = ct >> 3;            // 0/1 -> global y = y0+cy
    const int xt = ct & 7;

    float4_t a0 = {0.f,0.f,0.f,0.f};
#pragma unroll
    for (int sh=0; sh<9; sh++){
      const int dyr = sh/3, dx = sh - dyr*3;
      const int col = xt*16 + lr + dx;
      const int mof = ((cy+1+dyr)*TROW + col)*TCH;   // main tile (msg) cell
      const int rof = ((cy+dyr)*TROW + col)*12;      // rh tile cell
      short8_t bfv;
      if (lk == 0){
        bfv = *reinterpret_cast<const short8_t*>(&tl[mof]);
      } else if (lk == 1){
        union { short8_t v; unsigned u[4]; } tmp;
        tmp.u[0] = *reinterpret_cast<const unsigned*>(&tl[mof + 8]);  // msg ch 8,9
        tmp.u[1] = 0u;                                                // slots 10,11
        uint2 r0 = *reinterpret_cast<const uint2*>(&rhl[rof]);        // rh 0..3
        tmp.u[2] = r0.x; tmp.u[3] = r0.y;
        bfv = tmp.v;
      } else if (lk == 2){
        union { short8_t v; unsigned u[4]; } tmp;
        uint2 r0 = *reinterpret_cast<const uint2*>(&rhl[rof + 4]);    // rh 4..7
        uint2 r1 = *reinterpret_cast<const uint2*>(&rhl[rof + 8]);    // rh 8,9 + pad
        tmp.u[0] = r0.x; tmp.u[1] = r0.y; tmp.u[2] = r1.x; tmp.u[3] = r1.y;
        bfv = tmp.v;
      } else {
        bfv = zz;
      }
      a0 = __builtin_amdgcn_mfma_f32_16x16x32_bf16(wac[sh], bfv, a0, 0,0,0);
    }

    const int px = xt*16 + lr;
    const int y  = y0 + cy;
#pragma unroll
    for (int j=0;j<4;j++){
      const int o = lk*4 + j;
      if (o < 10){
        float cand = tanh_(a0[j] + bsc[j]);
        float uu = bf2f(ul[(cy*TROW + px + 1)*12 + o]);
        float hh = bf2f(tl[((cy+2)*TROW + px + 1)*TCH + 10 + o]);
        out[(size_t)(base_nb+o)*HW + y*WID + px] = (1.f-uu)*hh + uu*cand;
      }
    }
  }
}

// ---------------------------------------------------------------------------
extern "C" void kernel_launch(void* const* d_in, const int* in_sizes, int n_in,
                              void* d_out, int out_size, void* d_ws, size_t ws_size,
                              hipStream_t stream)
{
  (void)in_sizes; (void)n_in; (void)out_size; (void)ws_size;
  const float* hn   = (const float*)d_in[1];
  const float* pnn  = (const float*)d_in[2];
  const float* xp   = (const float*)d_in[3];
  const float* Wdau = (const float*)d_in[4];
  const float* bdau = (const float*)d_in[5];
  const float* Wdal = (const float*)d_in[6];
  const float* bdal = (const float*)d_in[7];
  const float* Wd1  = (const float*)d_in[8];
  const float* s1v  = (const float*)d_in[9];
  const float* t1v  = (const float*)d_in[10];
  const float* Wd2  = (const float*)d_in[11];
  const float* s2v  = (const float*)d_in[12];
  const float* t2v  = (const float*)d_in[13];
  const float* Wa0  = (const float*)d_in[14];
  const float* Wa1  = (const float*)d_in[15];
  const float* Wa2  = (const float*)d_in[16];
  const float* Wa3  = (const float*)d_in[17];
  const float* Wa4  = (const float*)d_in[18];
  const float* Wa5  = (const float*)d_in[19];
  const float* batt = (const float*)d_in[20];
  const float* Wp   = (const float*)d_in[21];
  const float* ps   = (const float*)d_in[22];
  const float* pt   = (const float*)d_in[23];
  const float* Wg   = (const float*)d_in[24];
  const float* bg   = (const float*)d_in[25];
  const float* Wc   = (const float*)d_in[26];
  const float* bc   = (const float*)d_in[27];

  float* out = (float*)d_out;
  float* wsf = (float*)d_ws;
  float* ws_msg = wsf;               // [6*4*10*HW] floats

  k_att_dec<<<dim3(1536), dim3(256), 0, stream>>>(hn, pnn, Wdau, bdau, Wdal, bdal,
      Wd1, s1v, t1v, Wd2, s2v, t2v, Wa0, Wa1, Wa2, Wa3, Wa4, Wa5, batt, out, ws_msg);
  k_proj<<<dim3(1024), dim3(256), 0, stream>>>(xp, Wp, ps, pt, (const float*)d_out, ws_msg);
  k_gru_fused<<<dim3(1536), dim3(256), 0, stream>>>(pnn, Wg, bg, Wc, bc, ws_msg, out);
}

// Round 11
// 133.242 us; speedup vs baseline: 1.0087x; 1.0087x over previous
//
#include <hip/hip_runtime.h>
#include <math.h>

#define HW    16384
#define WID   128
#define NB    4
// output section offsets (floats)
#define OFF_U 3932160
#define OFF_L 4259840
#define OFF_F 4456448

// conv tile geometry (ch-interleaved bf16): [4 rows][132 x][24 ch]
#define TCH   24
#define TROW  132
#define TILE_ELEMS (4*TROW*TCH)   // 12672 shorts = 25.3 KB -> 6 blocks/CU
#define WG_N   (9*32*TCH)         // 6912 shorts (staged inside tl, then overwritten)
#define WC_N   (9*16*TCH)         // 3456 shorts

typedef __attribute__((ext_vector_type(8))) short  short8_t;
typedef __attribute__((ext_vector_type(4))) float  float4_t;

__device__ __forceinline__ float sig_(float x)  { return 1.f/(1.f+__expf(-x)); }
__device__ __forceinline__ float tanh_(float x) { float e=__expf(2.f*x); return 1.f - 2.f/(e+1.f); }
__device__ __forceinline__ unsigned short f2bf(float x){          // RNE fp32->bf16
  unsigned u = __float_as_uint(x);
  return (unsigned short)((u + 0x7fffu + ((u>>16)&1u)) >> 16);
}
__device__ __forceinline__ float bf2f(unsigned short s){
  return __uint_as_float(((unsigned)s) << 16);
}

// ---------------------------------------------------------------------------
// Kernel A: node-split (grid 1536 = 6 nodes x 256 pixel-blocks)  [unchanged]
// ---------------------------------------------------------------------------
__global__ __launch_bounds__(256)
void k_att_dec(const float* __restrict__ hn, const float* __restrict__ pnn,
               const float* __restrict__ Wdau, const float* __restrict__ bdau,
               const float* __restrict__ Wdal, const float* __restrict__ bdal,
               const float* __restrict__ Wd1, const float* __restrict__ s1v, const float* __restrict__ t1v,
               const float* __restrict__ Wd2, const float* __restrict__ s2v, const float* __restrict__ t2v,
               const float* __restrict__ Wa0, const float* __restrict__ Wa1, const float* __restrict__ Wa2,
               const float* __restrict__ Wa3, const float* __restrict__ Wa4, const float* __restrict__ Wa5,
               const float* __restrict__ batt,
               float* __restrict__ out, float* __restrict__ wmsg)
{
  const int n   = blockIdx.x >> 8;
  const int g   = (blockIdx.x & 255)*256 + threadIdx.x;
  const int b   = g >> 14;
  const int pix = g & 16383;

  float h[10];
  float a;
  if (n < 4){
#pragma unroll
    for (int c=0;c<10;c++) h[c] = hn[(b*10+c)*HW + pix];
    float v[5]; float mx = -1e30f;
#pragma unroll
    for (int o=0;o<5;o++){
      float t = bdau[o];
#pragma unroll
      for (int c=0;c<10;c++) t += Wdau[o*10+c]*h[c];
      if (n==0) out[OFF_U + (b*5+o)*HW + pix] = t;
      v[o]=t; mx = fmaxf(mx,t);
    }
    float s=0.f;
#pragma unroll
    for (int o=0;o<5;o++){ v[o]=__expf(v[o]-mx); s+=v[o]; }
    a = v[n+1]/s;
  } else {
#pragma unroll
    for (int c=0;c<10;c++) h[c] = hn[((NB+b)*10+c)*HW + pix];
    float v[3]; float mx = -1e30f;
#pragma unroll
    for (int o=0;o<3;o++){
      float t = bdal[o];
#pragma unroll
      for (int c=0;c<10;c++) t += Wdal[o*10+c]*h[c];
      if (n==4) out[OFF_L + (b*3+o)*HW + pix] = t;
      v[o]=t; mx = fmaxf(mx,t);
    }
    float s=0.f;
#pragma unroll
    for (int o=0;o<3;o++){ v[o]=__expf(v[o]-mx); s+=v[o]; }
    a = v[n-3]/s;
  }

  float child[10];
#pragma unroll
  for (int c=0;c<10;c++) child[c] = pnn[((n*NB+b)*10+c)*HW + pix];

  float af = batt[n];
  if (n==0){
#pragma unroll
    for (int c=0;c<10;c++) af += Wa0[c]*pnn[((1*NB+b)*10+c)*HW+pix];
  } else if (n==1){
#pragma unroll
    for (int c=0;c<10;c++){
      af += Wa1[c]   *pnn[((0*NB+b)*10+c)*HW+pix];
      af += Wa1[10+c]*pnn[((2*NB+b)*10+c)*HW+pix];
      af += Wa1[20+c]*pnn[((3*NB+b)*10+c)*HW+pix];
      af += Wa1[30+c]*pnn[((4*NB+b)*10+c)*HW+pix];
    }
  } else if (n==2){
#pragma unroll
    for (int c=0;c<10;c++) af += Wa2[c]*pnn[((1*NB+b)*10+c)*HW+pix];
  } else if (n==3){
#pragma unroll
    for (int c=0;c<10;c++) af += Wa3[c]*pnn[((1*NB+b)*10+c)*HW+pix];
  } else if (n==4){
#pragma unroll
    for (int c=0;c<10;c++){
      af += Wa4[c]   *pnn[((1*NB+b)*10+c)*HW+pix];
      af += Wa4[10+c]*pnn[((5*NB+b)*10+c)*HW+pix];
    }
  } else {
#pragma unroll
    for (int c=0;c<10;c++) af += Wa5[c]*pnn[((4*NB+b)*10+c)*HW+pix];
  }
  out[OFF_F + (n*NB+b)*HW + pix] = sig_(af);

  float x20[20];
#pragma unroll
  for (int c=0;c<10;c++){ x20[c]=h[c]*a; x20[10+c]=child[c]; }
  float h20[20];
#pragma unroll
  for (int o=0;o<20;o++){
    float acc=0.f;
#pragma unroll
    for (int c=0;c<20;c++) acc += Wd1[o*20+c]*x20[c];
    h20[o] = fmaxf(acc*s1v[o]+t1v[o], 0.f);
  }
#pragma unroll
  for (int o=0;o<10;o++){
    float acc=0.f;
#pragma unroll
    for (int c=0;c<20;c++) acc += Wd2[o*20+c]*h20[c];
    wmsg[((n*NB+b)*10+o)*HW + pix] = fmaxf(acc*s2v[o]+t2v[o], 0.f);
  }
}

// ---------------------------------------------------------------------------
// Kernel B: projection GEMM v3 (unchanged from round 9)
// ---------------------------------------------------------------------------
__global__ __launch_bounds__(256, 2)
void k_proj(const float* __restrict__ xp, const float* __restrict__ Wp,
            const float* __restrict__ ps, const float* __restrict__ pt,
            const float* __restrict__ outf, float* __restrict__ wmsg)
{
  __shared__ __align__(16) unsigned short wlds[64*264];
  const int tid = threadIdx.x;

#pragma unroll
  for (int it=0; it<16; ++it){
    const int e = tid + it*256;
    const int row = e >> 6, q = e & 63;
    uint2 pk; pk.x = 0u; pk.y = 0u;
    if (row < 60){
      const float s = ps[row];
      float4 wv = *reinterpret_cast<const float4*>(Wp + row*256 + q*4);
      pk.x = (unsigned)f2bf(wv.x*s) | ((unsigned)f2bf(wv.y*s)<<16);
      pk.y = (unsigned)f2bf(wv.z*s) | ((unsigned)f2bf(wv.w*s)<<16);
    }
    *reinterpret_cast<uint2*>(&wlds[row*264 + q*4]) = pk;
  }
  __syncthreads();

  const int l  = tid & 63;
  const int w  = tid >> 6;
  const int lr = l & 15;
  const int lk = l >> 4;

  const int tile = blockIdx.x*4 + w;
  const int P    = tile*16;
  const int b    = P >> 14;
  const int pixb = P & 16383;
  const int px   = pixb + lr;

  const float* xb = xp + (size_t)(b*256)*HW + px;
  float v[64];
#pragma unroll
  for (int ks=0; ks<8; ++ks)
#pragma unroll
    for (int j=0; j<8; ++j)
      v[ks*8+j] = xb[(size_t)(ks*32 + lk*8 + j)*HW];

  short8_t bf[8];
#pragma unroll
  for (int ks=0; ks<8; ++ks)
#pragma unroll
    for (int j=0; j<8; ++j)
      bf[ks][j] = (short)f2bf(v[ks*8+j]);

  float4_t acc[4];
#pragma unroll
  for (int nf=0;nf<4;nf++){ acc[nf][0]=0.f; acc[nf][1]=0.f; acc[nf][2]=0.f; acc[nf][3]=0.f; }

#pragma unroll
  for (int ks=0; ks<8; ++ks){
#pragma unroll
    for (int nf=0; nf<4; ++nf){
      short8_t wa = *reinterpret_cast<const short8_t*>(&wlds[(nf*16+lr)*264 + ks*32 + lk*8]);
      acc[nf] = __builtin_amdgcn_mfma_f32_16x16x32_bf16(wa, bf[ks], acc[nf], 0,0,0);
    }
  }

#pragma unroll
  for (int nf=0;nf<4;nf++){
#pragma unroll
    for (int j=0;j<4;j++){
      const int row = nf*16 + lk*4 + j;
      if (row < 60){
        const unsigned nn = (unsigned)row / 10u;
        const int o = row - (int)nn*10;
        float att = outf[OFF_F + (nn*NB+b)*HW + pixb + lr];
        float val = fmaxf((2.f - att)*acc[nf][j] + pt[row], 0.f);
        size_t idx = ((size_t)((nn*NB+b)*10 + o))*HW + pixb + lr;
        wmsg[idx] += val;
      }
    }
  }
}

// ---------------------------------------------------------------------------
// Kernel C: GRU gates conv.  Weights staged through the SAME tl buffer
// (stage->frag-to-reg->re-zero->stage tile) so LDS = 25.3 KB -> 6 blocks/CU.
// rh and u written as packed bf16 channel-pairs: [nb][5][HW] unsigned.
// ---------------------------------------------------------------------------
__global__ __launch_bounds__(256, 6)
void k_gru_gates(const float* __restrict__ pnn, const float* __restrict__ Wg,
                 const float* __restrict__ bg,
                 const float* __restrict__ wmsg, unsigned* __restrict__ wrh_p,
                 unsigned* __restrict__ wu_p)
{
  __shared__ __align__(16) unsigned short tl[TILE_ELEMS];
  const int bi = blockIdx.x;
  const int n  = bi >> 8;
  const int b  = (bi >> 6) & 3;
  const int y0 = (bi & 63) * 2;
  const int tid = threadIdx.x;

  const int base_nb5 = (n*NB+b)*5;
  const float* msgb = wmsg + (size_t)((n*NB+b)*10)*HW;
  const float* pb   = pnn  + (size_t)((n*NB+b)*10)*HW;

  const int l  = tid & 63;
  const int w  = tid >> 6;
  const int lr = l & 15;
  const int lk = l >> 4;
  short8_t zz = {0,0,0,0,0,0,0,0};

  // ---- phase W: stage gates weights [9][32][24] into tl[0..WG_N) ----
#pragma unroll
  for (int it=0; it<4; ++it){ int e = tid*8 + it*2048; if (e < WG_N) *reinterpret_cast<short8_t*>(&tl[e]) = zz; }
  __syncthreads();
  const float* Wgn = Wg + n*3600;
#pragma unroll
  for (int it=0; it<8; ++it){
    const int e = tid + it*256;
    if (e < 1800){
      int sh = e/200, rem = e - sh*200, o = rem/10, chp = rem - o*10;
      float w0 = Wgn[o*180 + (2*chp  )*9 + sh];
      float w1 = Wgn[o*180 + (2*chp+1)*9 + sh];
      unsigned pk = (unsigned)f2bf(w0) | ((unsigned)f2bf(w1)<<16);
      *reinterpret_cast<unsigned*>(&tl[(sh*32+o)*TCH + 2*chp]) = pk;
    }
  }
  __syncthreads();
  short8_t wa0[9], wa1[9];
#pragma unroll
  for (int sh=0; sh<9; sh++){
    wa0[sh] = (lk<3) ? *reinterpret_cast<const short8_t*>(&tl[(sh*32 +      lr)*TCH + lk*8]) : zz;
    wa1[sh] = (lk<3) ? *reinterpret_cast<const short8_t*>(&tl[(sh*32 + 16 + lr)*TCH + lk*8]) : zz;
  }
  float bs0[4], bs1[4];
#pragma unroll
  for (int j=0;j<4;j++){
    bs0[j] = bg[n*20 + lk*4 + j];
    int o1 = 16 + lk*4 + j;
    bs1[j] = (o1 < 20) ? bg[n*20 + o1] : 0.f;
  }
  __syncthreads();

  // ---- phase T: zero + stage input tile [4 rows][132][24] ----
#pragma unroll
  for (int it=0; it<7; ++it){ int e = tid*8 + it*2048; if (e < TILE_ELEMS) *reinterpret_cast<short8_t*>(&tl[e]) = zz; }
  __syncthreads();
#pragma unroll
  for (int it=0; it<20; ++it){
    const int e = tid + it*256;
    int row = e/1280, rem = e - row*1280, chp = rem>>7, x = rem&127;
    int yy = y0 - 1 + row;
    if ((unsigned)yy < 128u){
      const float* s0 = (chp<5) ? (msgb + (size_t)(2*chp)*HW) : (pb + (size_t)(2*chp-10)*HW);
      float v0 = s0[yy*WID + x];
      float v1 = s0[HW + yy*WID + x];
      unsigned pk = (unsigned)f2bf(v0) | ((unsigned)f2bf(v1)<<16);
      *reinterpret_cast<unsigned*>(&tl[(row*TROW + x+1)*TCH + 2*chp]) = pk;
    }
  }
  __syncthreads();

  // ---- compute ----
  for (int t=0; t<4; ++t){
    const int tile  = w*4 + t;
    const int row_t = tile >> 3;
    const int xloc  = (tile & 7) * 16;

    float4_t a0 = {0.f,0.f,0.f,0.f}, a1 = {0.f,0.f,0.f,0.f};
#pragma unroll
    for (int sh=0; sh<9; sh++){
      const int dy = sh/3, dx = sh - dy*3;
      const int addr = ((row_t + dy)*TROW + (xloc + lr + dx))*TCH + lk*8;
      short8_t bfv = (lk<3) ? *reinterpret_cast<const short8_t*>(&tl[addr]) : zz;
      a0 = __builtin_amdgcn_mfma_f32_16x16x32_bf16(wa0[sh], bfv, a0, 0,0,0);
      a1 = __builtin_amdgcn_mfma_f32_16x16x32_bf16(wa1[sh], bfv, a1, 0,0,0);
    }

    const int pix = (y0 + row_t)*WID + xloc + lr;
#pragma unroll
    for (int jp=0; jp<2; ++jp){
      const int j0 = 2*jp;
      const int o  = lk*4 + j0;
      float g0 = sig_(a0[j0]   + bs0[j0]);
      float g1 = sig_(a0[j0+1] + bs0[j0+1]);
      if (o < 10){
        float h0 = pb[(size_t)o*HW + pix];
        float h1 = pb[(size_t)(o+1)*HW + pix];
        unsigned pk = (unsigned)f2bf(g0*h0) | ((unsigned)f2bf(g1*h1) << 16);
        wrh_p[((size_t)base_nb5 + (o>>1))*HW + pix] = pk;
      } else {
        unsigned pk = (unsigned)f2bf(g0) | ((unsigned)f2bf(g1) << 16);
        wu_p[((size_t)base_nb5 + ((o-10)>>1))*HW + pix] = pk;
      }
    }
    if (lk == 0){
#pragma unroll
      for (int jp=0; jp<2; ++jp){
        const int j0 = 2*jp;
        const int o1 = 16 + j0;                  // u ch 6..9
        float g0 = sig_(a1[j0]   + bs1[j0]);
        float g1 = sig_(a1[j0+1] + bs1[j0+1]);
        unsigned pk = (unsigned)f2bf(g0) | ((unsigned)f2bf(g1) << 16);
        wu_p[((size_t)base_nb5 + ((o1-10)>>1))*HW + pix] = pk;
      }
    }
  }
}

// ---------------------------------------------------------------------------
// Kernel D: candidate conv + GRU blend.  Same tl-reuse trick (25.3 KB LDS).
// rh staged from packed bf16 (single 4B loads); u unpacked from packed bf16.
// ---------------------------------------------------------------------------
__global__ __launch_bounds__(256, 6)
void k_gru_out(const float* __restrict__ pnn, const float* __restrict__ Wc,
               const float* __restrict__ bc,
               const float* __restrict__ wmsg, const unsigned* __restrict__ wrh_p,
               const unsigned* __restrict__ wu_p, float* __restrict__ out)
{
  __shared__ __align__(16) unsigned short tl[TILE_ELEMS];
  const int bi = blockIdx.x;
  const int n  = bi >> 8;
  const int b  = (bi >> 6) & 3;
  const int y0 = (bi & 63) * 2;
  const int tid = threadIdx.x;

  const int base_nb  = (n*NB+b)*10;
  const int base_nb5 = (n*NB+b)*5;
  const float* msgb = wmsg + (size_t)base_nb*HW;
  const float* pb   = pnn  + (size_t)base_nb*HW;

  const int l  = tid & 63;
  const int w  = tid >> 6;
  const int lr = l & 15;
  const int lk = l >> 4;
  short8_t zz = {0,0,0,0,0,0,0,0};

  // ---- phase W: stage cand weights [9][16][24] into tl[0..WC_N) ----
#pragma unroll
  for (int it=0; it<2; ++it){ int e = tid*8 + it*2048; if (e < WC_N) *reinterpret_cast<short8_t*>(&tl[e]) = zz; }
  __syncthreads();
  const float* Wcn = Wc + n*1800;
#pragma unroll
  for (int it=0; it<4; ++it){
    const int e = tid + it*256;
    if (e < 900){
      int sh = e/100, rem = e - sh*100, o = rem/10, chp = rem - o*10;
      float w0 = Wcn[o*180 + (2*chp  )*9 + sh];
      float w1 = Wcn[o*180 + (2*chp+1)*9 + sh];
      unsigned pk = (unsigned)f2bf(w0) | ((unsigned)f2bf(w1)<<16);
      *reinterpret_cast<unsigned*>(&tl[(sh*16+o)*TCH + 2*chp]) = pk;
    }
  }
  __syncthreads();
  short8_t wac[9];
#pragma unroll
  for (int sh=0; sh<9; sh++)
    wac[sh] = (lk<3) ? *reinterpret_cast<const short8_t*>(&tl[(sh*16 + lr)*TCH + lk*8]) : zz;
  float bsc[4];
#pragma unroll
  for (int j=0;j<4;j++){
    int o = lk*4 + j;
    bsc[j] = (o < 10) ? bc[n*10 + o] : 0.f;
  }
  __syncthreads();

  // ---- phase T: zero + stage tile (ch 0..9 = msg f32, ch 10..19 = rh packed bf16) ----
#pragma unroll
  for (int it=0; it<7; ++it){ int e = tid*8 + it*2048; if (e < TILE_ELEMS) *reinterpret_cast<short8_t*>(&tl[e]) = zz; }
  __syncthreads();
#pragma unroll
  for (int it=0; it<20; ++it){
    const int e = tid + it*256;
    int row = e/1280, rem = e - row*1280, chp = rem>>7, x = rem&127;
    int yy = y0 - 1 + row;
    if ((unsigned)yy < 128u){
      unsigned pk;
      if (chp < 5){
        const float* s0 = msgb + (size_t)(2*chp)*HW;
        float v0 = s0[yy*WID + x];
        float v1 = s0[HW + yy*WID + x];
        pk = (unsigned)f2bf(v0) | ((unsigned)f2bf(v1)<<16);
      } else {
        pk = wrh_p[((size_t)base_nb5 + (chp-5))*HW + yy*WID + x];
      }
      *reinterpret_cast<unsigned*>(&tl[(row*TROW + x+1)*TCH + 2*chp]) = pk;
    }
  }
  __syncthreads();

  // ---- compute ----
  for (int t=0; t<4; ++t){
    const int tile  = w*4 + t;
    const int row_t = tile >> 3;
    const int xloc  = (tile & 7) * 16;

    float4_t a0 = {0.f,0.f,0.f,0.f};
#pragma unroll
    for (int sh=0; sh<9; sh++){
      const int dy = sh/3, dx = sh - dy*3;
      const int addr = ((row_t + dy)*TROW + (xloc + lr + dx))*TCH + lk*8;
      short8_t bfv = (lk<3) ? *reinterpret_cast<const short8_t*>(&tl[addr]) : zz;
      a0 = __builtin_amdgcn_mfma_f32_16x16x32_bf16(wac[sh], bfv, a0, 0,0,0);
    }

    const int pix = (y0 + row_t)*WID + xloc + lr;
#pragma unroll
    for (int jp=0; jp<2; ++jp){
      const int j0 = 2*jp;
      const int o  = lk*4 + j0;
      if (o < 10){
        unsigned up = wu_p[((size_t)base_nb5 + (o>>1))*HW + pix];
        float u0 = bf2f((unsigned short)(up & 0xffffu));
        float u1 = bf2f((unsigned short)(up >> 16));
        float h0 = pb[(size_t)o*HW + pix];
        float h1 = pb[(size_t)(o+1)*HW + pix];
        float c0 = tanh_(a0[j0]   + bsc[j0]);
        float c1 = tanh_(a0[j0+1] + bsc[j0+1]);
        out[(size_t)(base_nb+o  )*HW + pix] = (1.f-u0)*h0 + u0*c0;
        out[(size_t)(base_nb+o+1)*HW + pix] = (1.f-u1)*h1 + u1*c1;
      }
    }
  }
}

// ---------------------------------------------------------------------------
extern "C" void kernel_launch(void* const* d_in, const int* in_sizes, int n_in,
                              void* d_out, int out_size, void* d_ws, size_t ws_size,
                              hipStream_t stream)
{
  (void)in_sizes; (void)n_in; (void)out_size; (void)ws_size;
  const float* hn   = (const float*)d_in[1];
  const float* pnn  = (const float*)d_in[2];
  const float* xp   = (const float*)d_in[3];
  const float* Wdau = (const float*)d_in[4];
  const float* bdau = (const float*)d_in[5];
  const float* Wdal = (const float*)d_in[6];
  const float* bdal = (const float*)d_in[7];
  const float* Wd1  = (const float*)d_in[8];
  const float* s1v  = (const float*)d_in[9];
  const float* t1v  = (const float*)d_in[10];
  const float* Wd2  = (const float*)d_in[11];
  const float* s2v  = (const float*)d_in[12];
  const float* t2v  = (const float*)d_in[13];
  const float* Wa0  = (const float*)d_in[14];
  const float* Wa1  = (const float*)d_in[15];
  const float* Wa2  = (const float*)d_in[16];
  const float* Wa3  = (const float*)d_in[17];
  const float* Wa4  = (const float*)d_in[18];
  const float* Wa5  = (const float*)d_in[19];
  const float* batt = (const float*)d_in[20];
  const float* Wp   = (const float*)d_in[21];
  const float* ps   = (const float*)d_in[22];
  const float* pt   = (const float*)d_in[23];
  const float* Wg   = (const float*)d_in[24];
  const float* bg   = (const float*)d_in[25];
  const float* Wc   = (const float*)d_in[26];
  const float* bc   = (const float*)d_in[27];

  float* out = (float*)d_out;
  float* wsf = (float*)d_ws;
  float*    ws_msg = wsf;                               // 3,932,160 floats
  unsigned* ws_rh  = (unsigned*)(wsf + 3932160);        // 1,966,080 u32 (bf16 pairs)
  unsigned* ws_u   = ws_rh + 1966080;                   // 1,966,080 u32

  k_att_dec<<<dim3(1536), dim3(256), 0, stream>>>(hn, pnn, Wdau, bdau, Wdal, bdal,
      Wd1, s1v, t1v, Wd2, s2v, t2v, Wa0, Wa1, Wa2, Wa3, Wa4, Wa5, batt, out, ws_msg);
  k_proj<<<dim3(1024), dim3(256), 0, stream>>>(xp, Wp, ps, pt, (const float*)d_out, ws_msg);
  k_gru_gates<<<dim3(1536), dim3(256), 0, stream>>>(pnn, Wg, bg, ws_msg, ws_rh, ws_u);
  k_gru_out<<<dim3(1536), dim3(256), 0, stream>>>(pnn, Wc, bc, ws_msg, ws_rh, ws_u, out);
}

// Round 12
// 113.714 us; speedup vs baseline: 1.1819x; 1.1717x over previous
//
#include <hip/hip_runtime.h>
#include <math.h>

#define HW    16384
#define WID   128
#define NB    4
// output section offsets (floats)
#define OFF_U 3932160
#define OFF_L 4259840
#define OFF_F 4456448

// conv tile geometry (ch-interleaved bf16): [4 rows][132 x][24 ch]
#define TCH   24
#define TROW  132
#define TILE_ELEMS (4*TROW*TCH)   // 12672 shorts = 25.3 KB
#define WG_ELEMS   (9*32*TCH)     // 6912 shorts  = 13.8 KB
#define WC_ELEMS   (9*16*TCH)     // 3456 shorts  =  6.9 KB

typedef __attribute__((ext_vector_type(8))) short  short8_t;
typedef __attribute__((ext_vector_type(4))) float  float4_t;

__device__ __forceinline__ float sig_(float x)  { return 1.f/(1.f+__expf(-x)); }
__device__ __forceinline__ float tanh_(float x) { float e=__expf(2.f*x); return 1.f - 2.f/(e+1.f); }
__device__ __forceinline__ unsigned short f2bf(float x){          // RNE fp32->bf16
  unsigned u = __float_as_uint(x);
  return (unsigned short)((u + 0x7fffu + ((u>>16)&1u)) >> 16);
}
// XCD-aware bijective swizzle for 1536-block grids (1536 = 8*192):
// consecutive work ids land on the same XCD's L2.
__device__ __forceinline__ int swz1536(int bi){ return (bi & 7)*192 + (bi >> 3); }

// ---------------------------------------------------------------------------
// Kernel A: node-split (grid 1536 = 6 nodes x 256 pixel-blocks) + XCD swizzle
// ---------------------------------------------------------------------------
__global__ __launch_bounds__(256)
void k_att_dec(const float* __restrict__ hn, const float* __restrict__ pnn,
               const float* __restrict__ Wdau, const float* __restrict__ bdau,
               const float* __restrict__ Wdal, const float* __restrict__ bdal,
               const float* __restrict__ Wd1, const float* __restrict__ s1v, const float* __restrict__ t1v,
               const float* __restrict__ Wd2, const float* __restrict__ s2v, const float* __restrict__ t2v,
               const float* __restrict__ Wa0, const float* __restrict__ Wa1, const float* __restrict__ Wa2,
               const float* __restrict__ Wa3, const float* __restrict__ Wa4, const float* __restrict__ Wa5,
               const float* __restrict__ batt,
               float* __restrict__ out, float* __restrict__ wmsg)
{
  const int bi  = swz1536(blockIdx.x);
  const int n   = bi >> 8;
  const int g   = (bi & 255)*256 + threadIdx.x;
  const int b   = g >> 14;
  const int pix = g & 16383;

  float h[10];
  float a;
  if (n < 4){
#pragma unroll
    for (int c=0;c<10;c++) h[c] = hn[(b*10+c)*HW + pix];
    float v[5]; float mx = -1e30f;
#pragma unroll
    for (int o=0;o<5;o++){
      float t = bdau[o];
#pragma unroll
      for (int c=0;c<10;c++) t += Wdau[o*10+c]*h[c];
      if (n==0) out[OFF_U + (b*5+o)*HW + pix] = t;
      v[o]=t; mx = fmaxf(mx,t);
    }
    float s=0.f;
#pragma unroll
    for (int o=0;o<5;o++){ v[o]=__expf(v[o]-mx); s+=v[o]; }
    a = v[n+1]/s;
  } else {
#pragma unroll
    for (int c=0;c<10;c++) h[c] = hn[((NB+b)*10+c)*HW + pix];
    float v[3]; float mx = -1e30f;
#pragma unroll
    for (int o=0;o<3;o++){
      float t = bdal[o];
#pragma unroll
      for (int c=0;c<10;c++) t += Wdal[o*10+c]*h[c];
      if (n==4) out[OFF_L + (b*3+o)*HW + pix] = t;
      v[o]=t; mx = fmaxf(mx,t);
    }
    float s=0.f;
#pragma unroll
    for (int o=0;o<3;o++){ v[o]=__expf(v[o]-mx); s+=v[o]; }
    a = v[n-3]/s;
  }

  float child[10];
#pragma unroll
  for (int c=0;c<10;c++) child[c] = pnn[((n*NB+b)*10+c)*HW + pix];

  float af = batt[n];
  if (n==0){
#pragma unroll
    for (int c=0;c<10;c++) af += Wa0[c]*pnn[((1*NB+b)*10+c)*HW+pix];
  } else if (n==1){
#pragma unroll
    for (int c=0;c<10;c++){
      af += Wa1[c]   *pnn[((0*NB+b)*10+c)*HW+pix];
      af += Wa1[10+c]*pnn[((2*NB+b)*10+c)*HW+pix];
      af += Wa1[20+c]*pnn[((3*NB+b)*10+c)*HW+pix];
      af += Wa1[30+c]*pnn[((4*NB+b)*10+c)*HW+pix];
    }
  } else if (n==2){
#pragma unroll
    for (int c=0;c<10;c++) af += Wa2[c]*pnn[((1*NB+b)*10+c)*HW+pix];
  } else if (n==3){
#pragma unroll
    for (int c=0;c<10;c++) af += Wa3[c]*pnn[((1*NB+b)*10+c)*HW+pix];
  } else if (n==4){
#pragma unroll
    for (int c=0;c<10;c++){
      af += Wa4[c]   *pnn[((1*NB+b)*10+c)*HW+pix];
      af += Wa4[10+c]*pnn[((5*NB+b)*10+c)*HW+pix];
    }
  } else {
#pragma unroll
    for (int c=0;c<10;c++) af += Wa5[c]*pnn[((4*NB+b)*10+c)*HW+pix];
  }
  out[OFF_F + (n*NB+b)*HW + pix] = sig_(af);

  float x20[20];
#pragma unroll
  for (int c=0;c<10;c++){ x20[c]=h[c]*a; x20[10+c]=child[c]; }
  float h20[20];
#pragma unroll
  for (int o=0;o<20;o++){
    float acc=0.f;
#pragma unroll
    for (int c=0;c<20;c++) acc += Wd1[o*20+c]*x20[c];
    h20[o] = fmaxf(acc*s1v[o]+t1v[o], 0.f);
  }
#pragma unroll
  for (int o=0;o<10;o++){
    float acc=0.f;
#pragma unroll
    for (int c=0;c<20;c++) acc += Wd2[o*20+c]*h20[c];
    wmsg[((n*NB+b)*10+o)*HW + pix] = fmaxf(acc*s2v[o]+t2v[o], 0.f);
  }
}

// ---------------------------------------------------------------------------
// Kernel B: projection GEMM v3 (unchanged from round 9)
// ---------------------------------------------------------------------------
__global__ __launch_bounds__(256, 2)
void k_proj(const float* __restrict__ xp, const float* __restrict__ Wp,
            const float* __restrict__ ps, const float* __restrict__ pt,
            const float* __restrict__ outf, float* __restrict__ wmsg)
{
  __shared__ __align__(16) unsigned short wlds[64*264];
  const int tid = threadIdx.x;

#pragma unroll
  for (int it=0; it<16; ++it){
    const int e = tid + it*256;
    const int row = e >> 6, q = e & 63;
    uint2 pk; pk.x = 0u; pk.y = 0u;
    if (row < 60){
      const float s = ps[row];
      float4 wv = *reinterpret_cast<const float4*>(Wp + row*256 + q*4);
      pk.x = (unsigned)f2bf(wv.x*s) | ((unsigned)f2bf(wv.y*s)<<16);
      pk.y = (unsigned)f2bf(wv.z*s) | ((unsigned)f2bf(wv.w*s)<<16);
    }
    *reinterpret_cast<uint2*>(&wlds[row*264 + q*4]) = pk;
  }
  __syncthreads();

  const int l  = tid & 63;
  const int w  = tid >> 6;
  const int lr = l & 15;
  const int lk = l >> 4;

  const int tile = blockIdx.x*4 + w;
  const int P    = tile*16;
  const int b    = P >> 14;
  const int pixb = P & 16383;
  const int px   = pixb + lr;

  const float* xb = xp + (size_t)(b*256)*HW + px;
  float v[64];
#pragma unroll
  for (int ks=0; ks<8; ++ks)
#pragma unroll
    for (int j=0; j<8; ++j)
      v[ks*8+j] = xb[(size_t)(ks*32 + lk*8 + j)*HW];

  short8_t bf[8];
#pragma unroll
  for (int ks=0; ks<8; ++ks)
#pragma unroll
    for (int j=0; j<8; ++j)
      bf[ks][j] = (short)f2bf(v[ks*8+j]);

  float4_t acc[4];
#pragma unroll
  for (int nf=0;nf<4;nf++){ acc[nf][0]=0.f; acc[nf][1]=0.f; acc[nf][2]=0.f; acc[nf][3]=0.f; }

#pragma unroll
  for (int ks=0; ks<8; ++ks){
#pragma unroll
    for (int nf=0; nf<4; ++nf){
      short8_t wa = *reinterpret_cast<const short8_t*>(&wlds[(nf*16+lr)*264 + ks*32 + lk*8]);
      acc[nf] = __builtin_amdgcn_mfma_f32_16x16x32_bf16(wa, bf[ks], acc[nf], 0,0,0);
    }
  }

#pragma unroll
  for (int nf=0;nf<4;nf++){
#pragma unroll
    for (int j=0;j<4;j++){
      const int row = nf*16 + lk*4 + j;
      if (row < 60){
        const unsigned nn = (unsigned)row / 10u;
        const int o = row - (int)nn*10;
        float att = outf[OFF_F + (nn*NB+b)*HW + pixb + lr];
        float val = fmaxf((2.f - att)*acc[nf][j] + pt[row], 0.f);
        size_t idx = ((size_t)((nn*NB+b)*10 + o))*HW + pixb + lr;
        wmsg[idx] += val;
      }
    }
  }
}

// ---------------------------------------------------------------------------
// Kernel C: GRU gates conv (round-9 structure: separate weight LDS, 4 blk/CU,
// float wrh/wu) + XCD swizzle.
// ---------------------------------------------------------------------------
__global__ __launch_bounds__(256, 4)
void k_gru_gates(const float* __restrict__ pnn, const float* __restrict__ Wg,
                 const float* __restrict__ bg,
                 const float* __restrict__ wmsg, float* __restrict__ wrh,
                 float* __restrict__ wu)
{
  __shared__ __align__(16) unsigned short tl[TILE_ELEMS];
  __shared__ __align__(16) unsigned short wl[WG_ELEMS];
  const int bi = swz1536(blockIdx.x);
  const int n  = bi >> 8;
  const int b  = (bi >> 6) & 3;
  const int y0 = (bi & 63) * 2;
  const int tid = threadIdx.x;

  const int base_nb = (n*NB+b)*10;
  const float* msgb = wmsg + (size_t)base_nb*HW;
  const float* pb   = pnn  + (size_t)base_nb*HW;

  short8_t zz = {0,0,0,0,0,0,0,0};
#pragma unroll
  for (int it=0; it<7; ++it){
    const int e = tid*8 + it*2048;
    if (e < TILE_ELEMS) *reinterpret_cast<short8_t*>(&tl[e]) = zz;
  }
#pragma unroll
  for (int it=0; it<4; ++it){
    const int e = tid*8 + it*2048;
    if (e < WG_ELEMS) *reinterpret_cast<short8_t*>(&wl[e]) = zz;
  }
  __syncthreads();

  const float* Wn = Wg + n*3600;
#pragma unroll
  for (int it=0; it<8; ++it){
    const int e = tid + it*256;
    if (e < 1800){
      int sh = e/200, rem = e - sh*200, o = rem/10, chp = rem - o*10;
      float w0 = Wn[o*180 + (2*chp  )*9 + sh];
      float w1 = Wn[o*180 + (2*chp+1)*9 + sh];
      unsigned pk = (unsigned)f2bf(w0) | ((unsigned)f2bf(w1)<<16);
      *reinterpret_cast<unsigned*>(&wl[(sh*32+o)*TCH + 2*chp]) = pk;
    }
  }
#pragma unroll
  for (int it=0; it<20; ++it){
    const int e = tid + it*256;           // e < 5120 always
    int row = e/1280, rem = e - row*1280, chp = rem>>7, x = rem&127;
    int yy = y0 - 1 + row;
    if ((unsigned)yy < 128u){
      const float* s0 = (chp<5) ? (msgb + (size_t)(2*chp)*HW) : (pb + (size_t)(2*chp-10)*HW);
      float v0 = s0[yy*WID + x];
      float v1 = s0[HW + yy*WID + x];
      unsigned pk = (unsigned)f2bf(v0) | ((unsigned)f2bf(v1)<<16);
      *reinterpret_cast<unsigned*>(&tl[(row*TROW + x+1)*TCH + 2*chp]) = pk;
    }
  }
  __syncthreads();

  const int l  = tid & 63;
  const int w  = tid >> 6;
  const int lr = l & 15;
  const int lk = l >> 4;

  short8_t wa0[9], wa1[9];
#pragma unroll
  for (int sh=0; sh<9; sh++){
    wa0[sh] = (lk<3) ? *reinterpret_cast<const short8_t*>(&wl[(sh*32 +      lr)*TCH + lk*8]) : zz;
    wa1[sh] = (lk<3) ? *reinterpret_cast<const short8_t*>(&wl[(sh*32 + 16 + lr)*TCH + lk*8]) : zz;
  }
  float bs0[4], bs1[4];
#pragma unroll
  for (int j=0;j<4;j++){
    int o = lk*4 + j;
    bs0[j] = bg[n*20 + o];
    int o1 = 16 + lk*4 + j;
    bs1[j] = (o1 < 20) ? bg[n*20 + o1] : 0.f;
  }

  for (int t=0; t<4; ++t){
    const int tile  = w*4 + t;
    const int row_t = tile >> 3;
    const int xloc  = (tile & 7) * 16;

    float4_t a0 = {0.f,0.f,0.f,0.f}, a1 = {0.f,0.f,0.f,0.f};
#pragma unroll
    for (int sh=0; sh<9; sh++){
      const int dy = sh/3, dx = sh - dy*3;
      const int addr = ((row_t + dy)*TROW + (xloc + lr + dx))*TCH + lk*8;
      short8_t bf = (lk<3) ? *reinterpret_cast<const short8_t*>(&tl[addr]) : zz;
      a0 = __builtin_amdgcn_mfma_f32_16x16x32_bf16(wa0[sh], bf, a0, 0,0,0);
      a1 = __builtin_amdgcn_mfma_f32_16x16x32_bf16(wa1[sh], bf, a1, 0,0,0);
    }

    const int pix = (y0 + row_t)*WID + xloc + lr;
#pragma unroll
    for (int j=0;j<4;j++){
      const int o = lk*4 + j;
      float g = sig_(a0[j] + bs0[j]);
      if (o < 10) wrh[(size_t)(base_nb+o)*HW + pix] = g * pb[(size_t)o*HW + pix];
      else        wu [(size_t)(base_nb+o-10)*HW + pix] = g;
      const int o1 = 16 + lk*4 + j;
      if (o1 < 20){
        float g1 = sig_(a1[j] + bs1[j]);
        wu[(size_t)(base_nb+o1-10)*HW + pix] = g1;
      }
    }
  }
}

// ---------------------------------------------------------------------------
// Kernel D: candidate conv + GRU blend (round-9 structure) + XCD swizzle
// ---------------------------------------------------------------------------
__global__ __launch_bounds__(256, 4)
void k_gru_out(const float* __restrict__ pnn, const float* __restrict__ Wc,
               const float* __restrict__ bc,
               const float* __restrict__ wmsg, const float* __restrict__ wrh,
               const float* __restrict__ wu, float* __restrict__ out)
{
  __shared__ __align__(16) unsigned short tl[TILE_ELEMS];
  __shared__ __align__(16) unsigned short wl[WC_ELEMS];
  const int bi = swz1536(blockIdx.x);
  const int n  = bi >> 8;
  const int b  = (bi >> 6) & 3;
  const int y0 = (bi & 63) * 2;
  const int tid = threadIdx.x;

  const int base_nb = (n*NB+b)*10;
  const float* msgb = wmsg + (size_t)base_nb*HW;
  const float* rhb  = wrh  + (size_t)base_nb*HW;
  const float* pb   = pnn  + (size_t)base_nb*HW;

  short8_t zz = {0,0,0,0,0,0,0,0};
#pragma unroll
  for (int it=0; it<7; ++it){
    const int e = tid*8 + it*2048;
    if (e < TILE_ELEMS) *reinterpret_cast<short8_t*>(&tl[e]) = zz;
  }
#pragma unroll
  for (int it=0; it<2; ++it){
    const int e = tid*8 + it*2048;
    if (e < WC_ELEMS) *reinterpret_cast<short8_t*>(&wl[e]) = zz;
  }
  __syncthreads();

  const float* Wn = Wc + n*1800;
#pragma unroll
  for (int it=0; it<4; ++it){
    const int e = tid + it*256;
    if (e < 900){
      int sh = e/100, rem = e - sh*100, o = rem/10, chp = rem - o*10;
      float w0 = Wn[o*180 + (2*chp  )*9 + sh];
      float w1 = Wn[o*180 + (2*chp+1)*9 + sh];
      unsigned pk = (unsigned)f2bf(w0) | ((unsigned)f2bf(w1)<<16);
      *reinterpret_cast<unsigned*>(&wl[(sh*16+o)*TCH + 2*chp]) = pk;
    }
  }
#pragma unroll
  for (int it=0; it<20; ++it){
    const int e = tid + it*256;
    int row = e/1280, rem = e - row*1280, chp = rem>>7, x = rem&127;
    int yy = y0 - 1 + row;
    if ((unsigned)yy < 128u){
      const float* s0 = (chp<5) ? (msgb + (size_t)(2*chp)*HW) : (rhb + (size_t)(2*chp-10)*HW);
      float v0 = s0[yy*WID + x];
      float v1 = s0[HW + yy*WID + x];
      unsigned pk = (unsigned)f2bf(v0) | ((unsigned)f2bf(v1)<<16);
      *reinterpret_cast<unsigned*>(&tl[(row*TROW + x+1)*TCH + 2*chp]) = pk;
    }
  }
  __syncthreads();

  const int l  = tid & 63;
  const int w  = tid >> 6;
  const int lr = l & 15;
  const int lk = l >> 4;

  short8_t wa[9];
#pragma unroll
  for (int sh=0; sh<9; sh++)
    wa[sh] = (lk<3) ? *reinterpret_cast<const short8_t*>(&wl[(sh*16 + lr)*TCH + lk*8]) : zz;

  float bs[4];
#pragma unroll
  for (int j=0;j<4;j++){
    int o = lk*4 + j;
    bs[j] = (o < 10) ? bc[n*10 + o] : 0.f;
  }

  for (int t=0; t<4; ++t){
    const int tile  = w*4 + t;
    const int row_t = tile >> 3;
    const int xloc  = (tile & 7) * 16;

    float4_t a0 = {0.f,0.f,0.f,0.f};
#pragma unroll
    for (int sh=0; sh<9; sh++){
      const int dy = sh/3, dx = sh - dy*3;
      const int addr = ((row_t + dy)*TROW + (xloc + lr + dx))*TCH + lk*8;
      short8_t bf = (lk<3) ? *reinterpret_cast<const short8_t*>(&tl[addr]) : zz;
      a0 = __builtin_amdgcn_mfma_f32_16x16x32_bf16(wa[sh], bf, a0, 0,0,0);
    }

    const int pix = (y0 + row_t)*WID + xloc + lr;
#pragma unroll
    for (int j=0;j<4;j++){
      const int o = lk*4 + j;
      if (o < 10){
        float cand = tanh_(a0[j] + bs[j]);
        float uu = wu[(size_t)(base_nb+o)*HW + pix];
        float hh = pb[(size_t)o*HW + pix];
        out[(size_t)(base_nb+o)*HW + pix] = (1.f-uu)*hh + uu*cand;
      }
    }
  }
}

// ---------------------------------------------------------------------------
extern "C" void kernel_launch(void* const* d_in, const int* in_sizes, int n_in,
                              void* d_out, int out_size, void* d_ws, size_t ws_size,
                              hipStream_t stream)
{
  (void)in_sizes; (void)n_in; (void)out_size; (void)ws_size;
  const float* hn   = (const float*)d_in[1];
  const float* pnn  = (const float*)d_in[2];
  const float* xp   = (const float*)d_in[3];
  const float* Wdau = (const float*)d_in[4];
  const float* bdau = (const float*)d_in[5];
  const float* Wdal = (const float*)d_in[6];
  const float* bdal = (const float*)d_in[7];
  const float* Wd1  = (const float*)d_in[8];
  const float* s1v  = (const float*)d_in[9];
  const float* t1v  = (const float*)d_in[10];
  const float* Wd2  = (const float*)d_in[11];
  const float* s2v  = (const float*)d_in[12];
  const float* t2v  = (const float*)d_in[13];
  const float* Wa0  = (const float*)d_in[14];
  const float* Wa1  = (const float*)d_in[15];
  const float* Wa2  = (const float*)d_in[16];
  const float* Wa3  = (const float*)d_in[17];
  const float* Wa4  = (const float*)d_in[18];
  const float* Wa5  = (const float*)d_in[19];
  const float* batt = (const float*)d_in[20];
  const float* Wp   = (const float*)d_in[21];
  const float* ps   = (const float*)d_in[22];
  const float* pt   = (const float*)d_in[23];
  const float* Wg   = (const float*)d_in[24];
  const float* bg   = (const float*)d_in[25];
  const float* Wc   = (const float*)d_in[26];
  const float* bc   = (const float*)d_in[27];

  float* out = (float*)d_out;
  float* wsf = (float*)d_ws;
  float* ws_msg = wsf;               // [6*4*10*HW] floats
  float* ws_rh  = wsf + 3932160;
  float* ws_u   = wsf + 7864320;

  k_att_dec<<<dim3(1536), dim3(256), 0, stream>>>(hn, pnn, Wdau, bdau, Wdal, bdal,
      Wd1, s1v, t1v, Wd2, s2v, t2v, Wa0, Wa1, Wa2, Wa3, Wa4, Wa5, batt, out, ws_msg);
  k_proj<<<dim3(1024), dim3(256), 0, stream>>>(xp, Wp, ps, pt, (const float*)d_out, ws_msg);
  k_gru_gates<<<dim3(1536), dim3(256), 0, stream>>>(pnn, Wg, bg, ws_msg, ws_rh, ws_u);
  k_gru_out<<<dim3(1536), dim3(256), 0, stream>>>(pnn, Wc, bc, ws_msg, ws_rh, ws_u, out);
}

// Round 13
// 108.709 us; speedup vs baseline: 1.2363x; 1.0460x over previous
//
#include <hip/hip_runtime.h>
#include <math.h>

#define HW    16384
#define WID   128
#define NB    4
// output section offsets (floats)
#define OFF_U 3932160
#define OFF_L 4259840
#define OFF_F 4456448

// conv tile geometry (ch-interleaved bf16): [6 rows][132 x][24 ch]
#define TCH   24
#define TROW  132
#define T6_N  (6*TROW*TCH)        // 19008 shorts = 38.0 KB
#define WG_ELEMS   (9*32*TCH)     // 6912 shorts  = 13.8 KB
#define WC_ELEMS   (9*16*TCH)     // 3456 shorts  =  6.9 KB

typedef __attribute__((ext_vector_type(8))) short  short8_t;
typedef __attribute__((ext_vector_type(4))) float  float4_t;

__device__ __forceinline__ float sig_(float x)  { return 1.f/(1.f+__expf(-x)); }
__device__ __forceinline__ float tanh_(float x) { float e=__expf(2.f*x); return 1.f - 2.f/(e+1.f); }
__device__ __forceinline__ unsigned short f2bf(float x){          // RNE fp32->bf16
  unsigned u = __float_as_uint(x);
  return (unsigned short)((u + 0x7fffu + ((u>>16)&1u)) >> 16);
}
// HW packed fp32->bf16 pair (dst.lo = bf16(a), dst.hi = bf16(b))
__device__ __forceinline__ unsigned pk2bf(float a, float b){
  unsigned r;
  asm("v_cvt_pk_bf16_f32 %0, %1, %2" : "=v"(r) : "v"(a), "v"(b));
  return r;
}
// XCD-aware bijective swizzles
__device__ __forceinline__ int swz1536(int bi){ return (bi & 7)*192 + (bi >> 3); }
__device__ __forceinline__ int swz768 (int bi){ return (bi & 7)*96  + (bi >> 3); }

// ---------------------------------------------------------------------------
// Kernel A: node-split (grid 1536) + XCD swizzle  [unchanged from round 12]
// ---------------------------------------------------------------------------
__global__ __launch_bounds__(256)
void k_att_dec(const float* __restrict__ hn, const float* __restrict__ pnn,
               const float* __restrict__ Wdau, const float* __restrict__ bdau,
               const float* __restrict__ Wdal, const float* __restrict__ bdal,
               const float* __restrict__ Wd1, const float* __restrict__ s1v, const float* __restrict__ t1v,
               const float* __restrict__ Wd2, const float* __restrict__ s2v, const float* __restrict__ t2v,
               const float* __restrict__ Wa0, const float* __restrict__ Wa1, const float* __restrict__ Wa2,
               const float* __restrict__ Wa3, const float* __restrict__ Wa4, const float* __restrict__ Wa5,
               const float* __restrict__ batt,
               float* __restrict__ out, float* __restrict__ wmsg)
{
  const int bi  = swz1536(blockIdx.x);
  const int n   = bi >> 8;
  const int g   = (bi & 255)*256 + threadIdx.x;
  const int b   = g >> 14;
  const int pix = g & 16383;

  float h[10];
  float a;
  if (n < 4){
#pragma unroll
    for (int c=0;c<10;c++) h[c] = hn[(b*10+c)*HW + pix];
    float v[5]; float mx = -1e30f;
#pragma unroll
    for (int o=0;o<5;o++){
      float t = bdau[o];
#pragma unroll
      for (int c=0;c<10;c++) t += Wdau[o*10+c]*h[c];
      if (n==0) out[OFF_U + (b*5+o)*HW + pix] = t;
      v[o]=t; mx = fmaxf(mx,t);
    }
    float s=0.f;
#pragma unroll
    for (int o=0;o<5;o++){ v[o]=__expf(v[o]-mx); s+=v[o]; }
    a = v[n+1]/s;
  } else {
#pragma unroll
    for (int c=0;c<10;c++) h[c] = hn[((NB+b)*10+c)*HW + pix];
    float v[3]; float mx = -1e30f;
#pragma unroll
    for (int o=0;o<3;o++){
      float t = bdal[o];
#pragma unroll
      for (int c=0;c<10;c++) t += Wdal[o*10+c]*h[c];
      if (n==4) out[OFF_L + (b*3+o)*HW + pix] = t;
      v[o]=t; mx = fmaxf(mx,t);
    }
    float s=0.f;
#pragma unroll
    for (int o=0;o<3;o++){ v[o]=__expf(v[o]-mx); s+=v[o]; }
    a = v[n-3]/s;
  }

  float child[10];
#pragma unroll
  for (int c=0;c<10;c++) child[c] = pnn[((n*NB+b)*10+c)*HW + pix];

  float af = batt[n];
  if (n==0){
#pragma unroll
    for (int c=0;c<10;c++) af += Wa0[c]*pnn[((1*NB+b)*10+c)*HW+pix];
  } else if (n==1){
#pragma unroll
    for (int c=0;c<10;c++){
      af += Wa1[c]   *pnn[((0*NB+b)*10+c)*HW+pix];
      af += Wa1[10+c]*pnn[((2*NB+b)*10+c)*HW+pix];
      af += Wa1[20+c]*pnn[((3*NB+b)*10+c)*HW+pix];
      af += Wa1[30+c]*pnn[((4*NB+b)*10+c)*HW+pix];
    }
  } else if (n==2){
#pragma unroll
    for (int c=0;c<10;c++) af += Wa2[c]*pnn[((1*NB+b)*10+c)*HW+pix];
  } else if (n==3){
#pragma unroll
    for (int c=0;c<10;c++) af += Wa3[c]*pnn[((1*NB+b)*10+c)*HW+pix];
  } else if (n==4){
#pragma unroll
    for (int c=0;c<10;c++){
      af += Wa4[c]   *pnn[((1*NB+b)*10+c)*HW+pix];
      af += Wa4[10+c]*pnn[((5*NB+b)*10+c)*HW+pix];
    }
  } else {
#pragma unroll
    for (int c=0;c<10;c++) af += Wa5[c]*pnn[((4*NB+b)*10+c)*HW+pix];
  }
  out[OFF_F + (n*NB+b)*HW + pix] = sig_(af);

  float x20[20];
#pragma unroll
  for (int c=0;c<10;c++){ x20[c]=h[c]*a; x20[10+c]=child[c]; }
  float h20[20];
#pragma unroll
  for (int o=0;o<20;o++){
    float acc=0.f;
#pragma unroll
    for (int c=0;c<20;c++) acc += Wd1[o*20+c]*x20[c];
    h20[o] = fmaxf(acc*s1v[o]+t1v[o], 0.f);
  }
#pragma unroll
  for (int o=0;o<10;o++){
    float acc=0.f;
#pragma unroll
    for (int c=0;c<20;c++) acc += Wd2[o*20+c]*h20[c];
    wmsg[((n*NB+b)*10+o)*HW + pix] = fmaxf(acc*s2v[o]+t2v[o], 0.f);
  }
}

// ---------------------------------------------------------------------------
// Kernel B: projection GEMM v3 + cvt_pk conversions
// ---------------------------------------------------------------------------
__global__ __launch_bounds__(256, 2)
void k_proj(const float* __restrict__ xp, const float* __restrict__ Wp,
            const float* __restrict__ ps, const float* __restrict__ pt,
            const float* __restrict__ outf, float* __restrict__ wmsg)
{
  __shared__ __align__(16) unsigned short wlds[64*264];
  const int tid = threadIdx.x;

#pragma unroll
  for (int it=0; it<16; ++it){
    const int e = tid + it*256;
    const int row = e >> 6, q = e & 63;
    uint2 pk; pk.x = 0u; pk.y = 0u;
    if (row < 60){
      const float s = ps[row];
      float4 wv = *reinterpret_cast<const float4*>(Wp + row*256 + q*4);
      pk.x = pk2bf(wv.x*s, wv.y*s);
      pk.y = pk2bf(wv.z*s, wv.w*s);
    }
    *reinterpret_cast<uint2*>(&wlds[row*264 + q*4]) = pk;
  }
  __syncthreads();

  const int l  = tid & 63;
  const int w  = tid >> 6;
  const int lr = l & 15;
  const int lk = l >> 4;

  const int tile = blockIdx.x*4 + w;
  const int P    = tile*16;
  const int b    = P >> 14;
  const int pixb = P & 16383;
  const int px   = pixb + lr;

  const float* xb = xp + (size_t)(b*256)*HW + px;
  float v[64];
#pragma unroll
  for (int ks=0; ks<8; ++ks)
#pragma unroll
    for (int j=0; j<8; ++j)
      v[ks*8+j] = xb[(size_t)(ks*32 + lk*8 + j)*HW];

  short8_t bf[8];
#pragma unroll
  for (int ks=0; ks<8; ++ks){
    union { short8_t s; unsigned u[4]; } bu;
#pragma unroll
    for (int jp=0; jp<4; ++jp)
      bu.u[jp] = pk2bf(v[ks*8+2*jp], v[ks*8+2*jp+1]);
    bf[ks] = bu.s;
  }

  float4_t acc[4];
#pragma unroll
  for (int nf=0;nf<4;nf++){ acc[nf][0]=0.f; acc[nf][1]=0.f; acc[nf][2]=0.f; acc[nf][3]=0.f; }

#pragma unroll
  for (int ks=0; ks<8; ++ks){
#pragma unroll
    for (int nf=0; nf<4; ++nf){
      short8_t wa = *reinterpret_cast<const short8_t*>(&wlds[(nf*16+lr)*264 + ks*32 + lk*8]);
      acc[nf] = __builtin_amdgcn_mfma_f32_16x16x32_bf16(wa, bf[ks], acc[nf], 0,0,0);
    }
  }

#pragma unroll
  for (int nf=0;nf<4;nf++){
#pragma unroll
    for (int j=0;j<4;j++){
      const int row = nf*16 + lk*4 + j;
      if (row < 60){
        const unsigned nn = (unsigned)row / 10u;
        const int o = row - (int)nn*10;
        float att = outf[OFF_F + (nn*NB+b)*HW + pixb + lr];
        float val = fmaxf((2.f - att)*acc[nf][j] + pt[row], 0.f);
        size_t idx = ((size_t)((nn*NB+b)*10 + o))*HW + pixb + lr;
        wmsg[idx] += val;
      }
    }
  }
}

// ---------------------------------------------------------------------------
// Kernel C: GRU gates conv, 4-row tiles (grid 768 = 6n x 4b x 32 ytiles),
// XCD swizzle, cvt_pk staging.  LDS 38.0+13.8 = 51.8 KB -> 3 blocks/CU.
// ---------------------------------------------------------------------------
__global__ __launch_bounds__(256, 3)
void k_gru_gates(const float* __restrict__ pnn, const float* __restrict__ Wg,
                 const float* __restrict__ bg,
                 const float* __restrict__ wmsg, float* __restrict__ wrh,
                 float* __restrict__ wu)
{
  __shared__ __align__(16) unsigned short tl[T6_N];
  __shared__ __align__(16) unsigned short wl[WG_ELEMS];
  const int bi = swz768(blockIdx.x);
  const int n  = bi >> 7;
  const int b  = (bi >> 5) & 3;
  const int y0 = (bi & 31) * 4;
  const int tid = threadIdx.x;

  const int base_nb = (n*NB+b)*10;
  const float* msgb = wmsg + (size_t)base_nb*HW;
  const float* pb   = pnn  + (size_t)base_nb*HW;

  short8_t zz = {0,0,0,0,0,0,0,0};
#pragma unroll
  for (int it=0; it<10; ++it){
    const int e = tid*8 + it*2048;
    if (e < T6_N) *reinterpret_cast<short8_t*>(&tl[e]) = zz;
  }
#pragma unroll
  for (int it=0; it<4; ++it){
    const int e = tid*8 + it*2048;
    if (e < WG_ELEMS) *reinterpret_cast<short8_t*>(&wl[e]) = zz;
  }
  __syncthreads();

  const float* Wn = Wg + n*3600;
#pragma unroll
  for (int it=0; it<8; ++it){
    const int e = tid + it*256;
    if (e < 1800){
      int sh = e/200, rem = e - sh*200, o = rem/10, chp = rem - o*10;
      float w0 = Wn[o*180 + (2*chp  )*9 + sh];
      float w1 = Wn[o*180 + (2*chp+1)*9 + sh];
      *reinterpret_cast<unsigned*>(&wl[(sh*32+o)*TCH + 2*chp]) = pk2bf(w0, w1);
    }
  }
  // input tile: 6 rows x 10 chp x 128  (e = row*1280 + chp*128 + x)
#pragma unroll
  for (int it=0; it<30; ++it){
    const int e = tid + it*256;           // e < 7680 always
    int row = e/1280, rem = e - row*1280, chp = rem>>7, x = rem&127;
    int yy = y0 - 1 + row;
    if ((unsigned)yy < 128u){
      const float* s0 = (chp<5) ? (msgb + (size_t)(2*chp)*HW) : (pb + (size_t)(2*chp-10)*HW);
      float v0 = s0[yy*WID + x];
      float v1 = s0[HW + yy*WID + x];
      *reinterpret_cast<unsigned*>(&tl[(row*TROW + x+1)*TCH + 2*chp]) = pk2bf(v0, v1);
    }
  }
  __syncthreads();

  const int l  = tid & 63;
  const int w  = tid >> 6;
  const int lr = l & 15;
  const int lk = l >> 4;

  short8_t wa0[9], wa1[9];
#pragma unroll
  for (int sh=0; sh<9; sh++){
    wa0[sh] = (lk<3) ? *reinterpret_cast<const short8_t*>(&wl[(sh*32 +      lr)*TCH + lk*8]) : zz;
    wa1[sh] = (lk<3) ? *reinterpret_cast<const short8_t*>(&wl[(sh*32 + 16 + lr)*TCH + lk*8]) : zz;
  }
  float bs0[4], bs1[4];
#pragma unroll
  for (int j=0;j<4;j++){
    int o = lk*4 + j;
    bs0[j] = bg[n*20 + o];
    int o1 = 16 + lk*4 + j;
    bs1[j] = (o1 < 20) ? bg[n*20 + o1] : 0.f;
  }

  for (int t=0; t<8; ++t){
    const int tile  = w*8 + t;
    const int row_t = tile >> 3;          // 0..3
    const int xloc  = (tile & 7) * 16;

    float4_t a0 = {0.f,0.f,0.f,0.f}, a1 = {0.f,0.f,0.f,0.f};
#pragma unroll
    for (int sh=0; sh<9; sh++){
      const int dy = sh/3, dx = sh - dy*3;
      const int addr = ((row_t + dy)*TROW + (xloc + lr + dx))*TCH + lk*8;
      short8_t bf = (lk<3) ? *reinterpret_cast<const short8_t*>(&tl[addr]) : zz;
      a0 = __builtin_amdgcn_mfma_f32_16x16x32_bf16(wa0[sh], bf, a0, 0,0,0);
      a1 = __builtin_amdgcn_mfma_f32_16x16x32_bf16(wa1[sh], bf, a1, 0,0,0);
    }

    const int pix = (y0 + row_t)*WID + xloc + lr;
#pragma unroll
    for (int j=0;j<4;j++){
      const int o = lk*4 + j;
      float g = sig_(a0[j] + bs0[j]);
      if (o < 10) wrh[(size_t)(base_nb+o)*HW + pix] = g * pb[(size_t)o*HW + pix];
      else        wu [(size_t)(base_nb+o-10)*HW + pix] = g;
      const int o1 = 16 + lk*4 + j;
      if (o1 < 20){
        float g1 = sig_(a1[j] + bs1[j]);
        wu[(size_t)(base_nb+o1-10)*HW + pix] = g1;
      }
    }
  }
}

// ---------------------------------------------------------------------------
// Kernel D: candidate conv + GRU blend, 4-row tiles + swizzle + cvt_pk
// ---------------------------------------------------------------------------
__global__ __launch_bounds__(256, 3)
void k_gru_out(const float* __restrict__ pnn, const float* __restrict__ Wc,
               const float* __restrict__ bc,
               const float* __restrict__ wmsg, const float* __restrict__ wrh,
               const float* __restrict__ wu, float* __restrict__ out)
{
  __shared__ __align__(16) unsigned short tl[T6_N];
  __shared__ __align__(16) unsigned short wl[WC_ELEMS];
  const int bi = swz768(blockIdx.x);
  const int n  = bi >> 7;
  const int b  = (bi >> 5) & 3;
  const int y0 = (bi & 31) * 4;
  const int tid = threadIdx.x;

  const int base_nb = (n*NB+b)*10;
  const float* msgb = wmsg + (size_t)base_nb*HW;
  const float* rhb  = wrh  + (size_t)base_nb*HW;
  const float* pb   = pnn  + (size_t)base_nb*HW;

  short8_t zz = {0,0,0,0,0,0,0,0};
#pragma unroll
  for (int it=0; it<10; ++it){
    const int e = tid*8 + it*2048;
    if (e < T6_N) *reinterpret_cast<short8_t*>(&tl[e]) = zz;
  }
#pragma unroll
  for (int it=0; it<2; ++it){
    const int e = tid*8 + it*2048;
    if (e < WC_ELEMS) *reinterpret_cast<short8_t*>(&wl[e]) = zz;
  }
  __syncthreads();

  const float* Wn = Wc + n*1800;
#pragma unroll
  for (int it=0; it<4; ++it){
    const int e = tid + it*256;
    if (e < 900){
      int sh = e/100, rem = e - sh*100, o = rem/10, chp = rem - o*10;
      float w0 = Wn[o*180 + (2*chp  )*9 + sh];
      float w1 = Wn[o*180 + (2*chp+1)*9 + sh];
      *reinterpret_cast<unsigned*>(&wl[(sh*16+o)*TCH + 2*chp]) = pk2bf(w0, w1);
    }
  }
#pragma unroll
  for (int it=0; it<30; ++it){
    const int e = tid + it*256;
    int row = e/1280, rem = e - row*1280, chp = rem>>7, x = rem&127;
    int yy = y0 - 1 + row;
    if ((unsigned)yy < 128u){
      const float* s0 = (chp<5) ? (msgb + (size_t)(2*chp)*HW) : (rhb + (size_t)(2*chp-10)*HW);
      float v0 = s0[yy*WID + x];
      float v1 = s0[HW + yy*WID + x];
      *reinterpret_cast<unsigned*>(&tl[(row*TROW + x+1)*TCH + 2*chp]) = pk2bf(v0, v1);
    }
  }
  __syncthreads();

  const int l  = tid & 63;
  const int w  = tid >> 6;
  const int lr = l & 15;
  const int lk = l >> 4;

  short8_t wa[9];
#pragma unroll
  for (int sh=0; sh<9; sh++)
    wa[sh] = (lk<3) ? *reinterpret_cast<const short8_t*>(&wl[(sh*16 + lr)*TCH + lk*8]) : zz;

  float bs[4];
#pragma unroll
  for (int j=0;j<4;j++){
    int o = lk*4 + j;
    bs[j] = (o < 10) ? bc[n*10 + o] : 0.f;
  }

  for (int t=0; t<8; ++t){
    const int tile  = w*8 + t;
    const int row_t = tile >> 3;
    const int xloc  = (tile & 7) * 16;

    float4_t a0 = {0.f,0.f,0.f,0.f};
#pragma unroll
    for (int sh=0; sh<9; sh++){
      const int dy = sh/3, dx = sh - dy*3;
      const int addr = ((row_t + dy)*TROW + (xloc + lr + dx))*TCH + lk*8;
      short8_t bf = (lk<3) ? *reinterpret_cast<const short8_t*>(&tl[addr]) : zz;
      a0 = __builtin_amdgcn_mfma_f32_16x16x32_bf16(wa[sh], bf, a0, 0,0,0);
    }

    const int pix = (y0 + row_t)*WID + xloc + lr;
#pragma unroll
    for (int j=0;j<4;j++){
      const int o = lk*4 + j;
      if (o < 10){
        float cand = tanh_(a0[j] + bs[j]);
        float uu = wu[(size_t)(base_nb+o)*HW + pix];
        float hh = pb[(size_t)o*HW + pix];
        out[(size_t)(base_nb+o)*HW + pix] = (1.f-uu)*hh + uu*cand;
      }
    }
  }
}

// ---------------------------------------------------------------------------
extern "C" void kernel_launch(void* const* d_in, const int* in_sizes, int n_in,
                              void* d_out, int out_size, void* d_ws, size_t ws_size,
                              hipStream_t stream)
{
  (void)in_sizes; (void)n_in; (void)out_size; (void)ws_size;
  const float* hn   = (const float*)d_in[1];
  const float* pnn  = (const float*)d_in[2];
  const float* xp   = (const float*)d_in[3];
  const float* Wdau = (const float*)d_in[4];
  const float* bdau = (const float*)d_in[5];
  const float* Wdal = (const float*)d_in[6];
  const float* bdal = (const float*)d_in[7];
  const float* Wd1  = (const float*)d_in[8];
  const float* s1v  = (const float*)d_in[9];
  const float* t1v  = (const float*)d_in[10];
  const float* Wd2  = (const float*)d_in[11];
  const float* s2v  = (const float*)d_in[12];
  const float* t2v  = (const float*)d_in[13];
  const float* Wa0  = (const float*)d_in[14];
  const float* Wa1  = (const float*)d_in[15];
  const float* Wa2  = (const float*)d_in[16];
  const float* Wa3  = (const float*)d_in[17];
  const float* Wa4  = (const float*)d_in[18];
  const float* Wa5  = (const float*)d_in[19];
  const float* batt = (const float*)d_in[20];
  const float* Wp   = (const float*)d_in[21];
  const float* ps   = (const float*)d_in[22];
  const float* pt   = (const float*)d_in[23];
  const float* Wg   = (const float*)d_in[24];
  const float* bg   = (const float*)d_in[25];
  const float* Wc   = (const float*)d_in[26];
  const float* bc   = (const float*)d_in[27];

  float* out = (float*)d_out;
  float* wsf = (float*)d_ws;
  float* ws_msg = wsf;               // [6*4*10*HW] floats
  float* ws_rh  = wsf + 3932160;
  float* ws_u   = wsf + 7864320;

  k_att_dec<<<dim3(1536), dim3(256), 0, stream>>>(hn, pnn, Wdau, bdau, Wdal, bdal,
      Wd1, s1v, t1v, Wd2, s2v, t2v, Wa0, Wa1, Wa2, Wa3, Wa4, Wa5, batt, out, ws_msg);
  k_proj<<<dim3(1024), dim3(256), 0, stream>>>(xp, Wp, ps, pt, (const float*)d_out, ws_msg);
  k_gru_gates<<<dim3(768), dim3(256), 0, stream>>>(pnn, Wg, bg, ws_msg, ws_rh, ws_u);
  k_gru_out<<<dim3(768), dim3(256), 0, stream>>>(pnn, Wc, bc, ws_msg, ws_rh, ws_u, out);
}

// Round 14
// 105.771 us; speedup vs baseline: 1.2706x; 1.0278x over previous
//
#include <hip/hip_runtime.h>
#include <math.h>

#define HW    16384
#define WID   128
#define NB    4
// output section offsets (floats)
#define OFF_U 3932160
#define OFF_L 4259840
#define OFF_F 4456448

// conv tile geometry (ch-interleaved bf16): [6 rows][132 x][24 ch]
#define TCH   24
#define TROW  132
#define T6_N  (6*TROW*TCH)        // 19008 shorts = 38.0 KB
#define WG_ELEMS   (9*32*TCH)     // 6912 shorts  = 13.8 KB
#define WC_ELEMS   (9*16*TCH)     // 3456 shorts  =  6.9 KB

typedef __attribute__((ext_vector_type(8))) short  short8_t;
typedef __attribute__((ext_vector_type(4))) float  float4_t;

__device__ __forceinline__ float sig_(float x)  { return 1.f/(1.f+__expf(-x)); }
__device__ __forceinline__ float tanh_(float x) { float e=__expf(2.f*x); return 1.f - 2.f/(e+1.f); }
// HW packed fp32->bf16 pair (dst.lo = bf16(a), dst.hi = bf16(b))
__device__ __forceinline__ unsigned pk2bf(float a, float b){
  unsigned r;
  asm("v_cvt_pk_bf16_f32 %0, %1, %2" : "=v"(r) : "v"(a), "v"(b));
  return r;
}
__device__ __forceinline__ float bf2f(unsigned short s){
  return __uint_as_float(((unsigned)s) << 16);
}
// XCD-aware bijective swizzles
__device__ __forceinline__ int swz1536(int bi){ return (bi & 7)*192 + (bi >> 3); }
__device__ __forceinline__ int swz768 (int bi){ return (bi & 7)*96  + (bi >> 3); }

// ---------------------------------------------------------------------------
// Kernel A: node-split (grid 1536) + XCD swizzle.  wmsg now PACKED bf16 pairs.
// ---------------------------------------------------------------------------
__global__ __launch_bounds__(256)
void k_att_dec(const float* __restrict__ hn, const float* __restrict__ pnn,
               const float* __restrict__ Wdau, const float* __restrict__ bdau,
               const float* __restrict__ Wdal, const float* __restrict__ bdal,
               const float* __restrict__ Wd1, const float* __restrict__ s1v, const float* __restrict__ t1v,
               const float* __restrict__ Wd2, const float* __restrict__ s2v, const float* __restrict__ t2v,
               const float* __restrict__ Wa0, const float* __restrict__ Wa1, const float* __restrict__ Wa2,
               const float* __restrict__ Wa3, const float* __restrict__ Wa4, const float* __restrict__ Wa5,
               const float* __restrict__ batt,
               float* __restrict__ out, unsigned* __restrict__ wmsg_p)
{
  const int bi  = swz1536(blockIdx.x);
  const int n   = bi >> 8;
  const int g   = (bi & 255)*256 + threadIdx.x;
  const int b   = g >> 14;
  const int pix = g & 16383;

  float h[10];
  float a;
  if (n < 4){
#pragma unroll
    for (int c=0;c<10;c++) h[c] = hn[(b*10+c)*HW + pix];
    float v[5]; float mx = -1e30f;
#pragma unroll
    for (int o=0;o<5;o++){
      float t = bdau[o];
#pragma unroll
      for (int c=0;c<10;c++) t += Wdau[o*10+c]*h[c];
      if (n==0) out[OFF_U + (b*5+o)*HW + pix] = t;
      v[o]=t; mx = fmaxf(mx,t);
    }
    float s=0.f;
#pragma unroll
    for (int o=0;o<5;o++){ v[o]=__expf(v[o]-mx); s+=v[o]; }
    a = v[n+1]/s;
  } else {
#pragma unroll
    for (int c=0;c<10;c++) h[c] = hn[((NB+b)*10+c)*HW + pix];
    float v[3]; float mx = -1e30f;
#pragma unroll
    for (int o=0;o<3;o++){
      float t = bdal[o];
#pragma unroll
      for (int c=0;c<10;c++) t += Wdal[o*10+c]*h[c];
      if (n==4) out[OFF_L + (b*3+o)*HW + pix] = t;
      v[o]=t; mx = fmaxf(mx,t);
    }
    float s=0.f;
#pragma unroll
    for (int o=0;o<3;o++){ v[o]=__expf(v[o]-mx); s+=v[o]; }
    a = v[n-3]/s;
  }

  float child[10];
#pragma unroll
  for (int c=0;c<10;c++) child[c] = pnn[((n*NB+b)*10+c)*HW + pix];

  float af = batt[n];
  if (n==0){
#pragma unroll
    for (int c=0;c<10;c++) af += Wa0[c]*pnn[((1*NB+b)*10+c)*HW+pix];
  } else if (n==1){
#pragma unroll
    for (int c=0;c<10;c++){
      af += Wa1[c]   *pnn[((0*NB+b)*10+c)*HW+pix];
      af += Wa1[10+c]*pnn[((2*NB+b)*10+c)*HW+pix];
      af += Wa1[20+c]*pnn[((3*NB+b)*10+c)*HW+pix];
      af += Wa1[30+c]*pnn[((4*NB+b)*10+c)*HW+pix];
    }
  } else if (n==2){
#pragma unroll
    for (int c=0;c<10;c++) af += Wa2[c]*pnn[((1*NB+b)*10+c)*HW+pix];
  } else if (n==3){
#pragma unroll
    for (int c=0;c<10;c++) af += Wa3[c]*pnn[((1*NB+b)*10+c)*HW+pix];
  } else if (n==4){
#pragma unroll
    for (int c=0;c<10;c++){
      af += Wa4[c]   *pnn[((1*NB+b)*10+c)*HW+pix];
      af += Wa4[10+c]*pnn[((5*NB+b)*10+c)*HW+pix];
    }
  } else {
#pragma unroll
    for (int c=0;c<10;c++) af += Wa5[c]*pnn[((4*NB+b)*10+c)*HW+pix];
  }
  out[OFF_F + (n*NB+b)*HW + pix] = sig_(af);

  float x20[20];
#pragma unroll
  for (int c=0;c<10;c++){ x20[c]=h[c]*a; x20[10+c]=child[c]; }
  float h20[20];
#pragma unroll
  for (int o=0;o<20;o++){
    float acc=0.f;
#pragma unroll
    for (int c=0;c<20;c++) acc += Wd1[o*20+c]*x20[c];
    h20[o] = fmaxf(acc*s1v[o]+t1v[o], 0.f);
  }
  float msg10[10];
#pragma unroll
  for (int o=0;o<10;o++){
    float acc=0.f;
#pragma unroll
    for (int c=0;c<20;c++) acc += Wd2[o*20+c]*h20[c];
    msg10[o] = fmaxf(acc*s2v[o]+t2v[o], 0.f);
  }
#pragma unroll
  for (int p=0;p<5;p++)
    wmsg_p[((size_t)((n*NB+b)*5 + p))*HW + pix] = pk2bf(msg10[2*p], msg10[2*p+1]);
}

// ---------------------------------------------------------------------------
// Kernel B: projection GEMM v3.  Epilogue does packed-bf16 RMW on wmsg
// (rows come in even/odd pairs within one node: row = nf*16+lk*4+j, even base).
// ---------------------------------------------------------------------------
__global__ __launch_bounds__(256, 2)
void k_proj(const float* __restrict__ xp, const float* __restrict__ Wp,
            const float* __restrict__ ps, const float* __restrict__ pt,
            const float* __restrict__ outf, unsigned* __restrict__ wmsg_p)
{
  __shared__ __align__(16) unsigned short wlds[64*264];
  const int tid = threadIdx.x;

#pragma unroll
  for (int it=0; it<16; ++it){
    const int e = tid + it*256;
    const int row = e >> 6, q = e & 63;
    uint2 pk; pk.x = 0u; pk.y = 0u;
    if (row < 60){
      const float s = ps[row];
      float4 wv = *reinterpret_cast<const float4*>(Wp + row*256 + q*4);
      pk.x = pk2bf(wv.x*s, wv.y*s);
      pk.y = pk2bf(wv.z*s, wv.w*s);
    }
    *reinterpret_cast<uint2*>(&wlds[row*264 + q*4]) = pk;
  }
  __syncthreads();

  const int l  = tid & 63;
  const int w  = tid >> 6;
  const int lr = l & 15;
  const int lk = l >> 4;

  const int tile = blockIdx.x*4 + w;
  const int P    = tile*16;
  const int b    = P >> 14;
  const int pixb = P & 16383;
  const int px   = pixb + lr;

  const float* xb = xp + (size_t)(b*256)*HW + px;
  float v[64];
#pragma unroll
  for (int ks=0; ks<8; ++ks)
#pragma unroll
    for (int j=0; j<8; ++j)
      v[ks*8+j] = xb[(size_t)(ks*32 + lk*8 + j)*HW];

  short8_t bf[8];
#pragma unroll
  for (int ks=0; ks<8; ++ks){
    union { short8_t s; unsigned u[4]; } bu;
#pragma unroll
    for (int jp=0; jp<4; ++jp)
      bu.u[jp] = pk2bf(v[ks*8+2*jp], v[ks*8+2*jp+1]);
    bf[ks] = bu.s;
  }

  float4_t acc[4];
#pragma unroll
  for (int nf=0;nf<4;nf++){ acc[nf][0]=0.f; acc[nf][1]=0.f; acc[nf][2]=0.f; acc[nf][3]=0.f; }

#pragma unroll
  for (int ks=0; ks<8; ++ks){
#pragma unroll
    for (int nf=0; nf<4; ++nf){
      short8_t wa = *reinterpret_cast<const short8_t*>(&wlds[(nf*16+lr)*264 + ks*32 + lk*8]);
      acc[nf] = __builtin_amdgcn_mfma_f32_16x16x32_bf16(wa, bf[ks], acc[nf], 0,0,0);
    }
  }

#pragma unroll
  for (int nf=0;nf<4;nf++){
#pragma unroll
    for (int jp=0;jp<2;jp++){
      const int row0 = nf*16 + lk*4 + 2*jp;       // even
      if (row0 < 60){
        const unsigned nn = (unsigned)row0 / 10u;
        const int o = row0 - (int)nn*10;          // even, o+1 same node
        float att = outf[OFF_F + (nn*NB+b)*HW + pixb + lr];
        float f   = 2.f - att;
        float v0 = fmaxf(f*acc[nf][2*jp]   + pt[row0],   0.f);
        float v1 = fmaxf(f*acc[nf][2*jp+1] + pt[row0+1], 0.f);
        size_t idx = ((size_t)((nn*NB+b)*5 + (o>>1)))*HW + pixb + lr;
        unsigned old = wmsg_p[idx];
        float d0 = bf2f((unsigned short)(old & 0xffffu)) + v0;
        float d1 = bf2f((unsigned short)(old >> 16))     + v1;
        wmsg_p[idx] = pk2bf(d0, d1);
      }
    }
  }
}

// ---------------------------------------------------------------------------
// Kernel C: GRU gates conv, 4-row tiles + XCD swizzle.  msg channels staged
// with ONE packed u32 load; pnn channels pair-loaded + cvt_pk.
// ---------------------------------------------------------------------------
__global__ __launch_bounds__(256, 3)
void k_gru_gates(const float* __restrict__ pnn, const float* __restrict__ Wg,
                 const float* __restrict__ bg,
                 const unsigned* __restrict__ wmsg_p, float* __restrict__ wrh,
                 float* __restrict__ wu)
{
  __shared__ __align__(16) unsigned short tl[T6_N];
  __shared__ __align__(16) unsigned short wl[WG_ELEMS];
  const int bi = swz768(blockIdx.x);
  const int n  = bi >> 7;
  const int b  = (bi >> 5) & 3;
  const int y0 = (bi & 31) * 4;
  const int tid = threadIdx.x;

  const int base_nb  = (n*NB+b)*10;
  const int base_nb5 = (n*NB+b)*5;
  const float* pb = pnn + (size_t)base_nb*HW;

  short8_t zz = {0,0,0,0,0,0,0,0};
#pragma unroll
  for (int it=0; it<10; ++it){
    const int e = tid*8 + it*2048;
    if (e < T6_N) *reinterpret_cast<short8_t*>(&tl[e]) = zz;
  }
#pragma unroll
  for (int it=0; it<4; ++it){
    const int e = tid*8 + it*2048;
    if (e < WG_ELEMS) *reinterpret_cast<short8_t*>(&wl[e]) = zz;
  }
  __syncthreads();

  const float* Wn = Wg + n*3600;
#pragma unroll
  for (int it=0; it<8; ++it){
    const int e = tid + it*256;
    if (e < 1800){
      int sh = e/200, rem = e - sh*200, o = rem/10, chp = rem - o*10;
      float w0 = Wn[o*180 + (2*chp  )*9 + sh];
      float w1 = Wn[o*180 + (2*chp+1)*9 + sh];
      *reinterpret_cast<unsigned*>(&wl[(sh*32+o)*TCH + 2*chp]) = pk2bf(w0, w1);
    }
  }
  // input tile: 6 rows x 10 chp x 128  (chp<5: packed msg; chp>=5: pnn f32)
#pragma unroll
  for (int it=0; it<30; ++it){
    const int e = tid + it*256;           // e < 7680 always
    int row = e/1280, rem = e - row*1280, chp = rem>>7, x = rem&127;
    int yy = y0 - 1 + row;
    if ((unsigned)yy < 128u){
      unsigned pk;
      if (chp < 5){
        pk = wmsg_p[((size_t)(base_nb5 + chp))*HW + yy*WID + x];
      } else {
        const float* s0 = pb + (size_t)(2*chp-10)*HW;
        pk = pk2bf(s0[yy*WID + x], s0[HW + yy*WID + x]);
      }
      *reinterpret_cast<unsigned*>(&tl[(row*TROW + x+1)*TCH + 2*chp]) = pk;
    }
  }
  __syncthreads();

  const int l  = tid & 63;
  const int w  = tid >> 6;
  const int lr = l & 15;
  const int lk = l >> 4;

  short8_t wa0[9], wa1[9];
#pragma unroll
  for (int sh=0; sh<9; sh++){
    wa0[sh] = (lk<3) ? *reinterpret_cast<const short8_t*>(&wl[(sh*32 +      lr)*TCH + lk*8]) : zz;
    wa1[sh] = (lk<3) ? *reinterpret_cast<const short8_t*>(&wl[(sh*32 + 16 + lr)*TCH + lk*8]) : zz;
  }
  float bs0[4], bs1[4];
#pragma unroll
  for (int j=0;j<4;j++){
    int o = lk*4 + j;
    bs0[j] = bg[n*20 + o];
    int o1 = 16 + lk*4 + j;
    bs1[j] = (o1 < 20) ? bg[n*20 + o1] : 0.f;
  }

  for (int t=0; t<8; ++t){
    const int tile  = w*8 + t;
    const int row_t = tile >> 3;          // 0..3
    const int xloc  = (tile & 7) * 16;

    float4_t a0 = {0.f,0.f,0.f,0.f}, a1 = {0.f,0.f,0.f,0.f};
#pragma unroll
    for (int sh=0; sh<9; sh++){
      const int dy = sh/3, dx = sh - dy*3;
      const int addr = ((row_t + dy)*TROW + (xloc + lr + dx))*TCH + lk*8;
      short8_t bf = (lk<3) ? *reinterpret_cast<const short8_t*>(&tl[addr]) : zz;
      a0 = __builtin_amdgcn_mfma_f32_16x16x32_bf16(wa0[sh], bf, a0, 0,0,0);
      a1 = __builtin_amdgcn_mfma_f32_16x16x32_bf16(wa1[sh], bf, a1, 0,0,0);
    }

    const int pix = (y0 + row_t)*WID + xloc + lr;
#pragma unroll
    for (int j=0;j<4;j++){
      const int o = lk*4 + j;
      float g = sig_(a0[j] + bs0[j]);
      if (o < 10) wrh[(size_t)(base_nb+o)*HW + pix] = g * pb[(size_t)o*HW + pix];
      else        wu [(size_t)(base_nb+o-10)*HW + pix] = g;
      const int o1 = 16 + lk*4 + j;
      if (o1 < 20){
        float g1 = sig_(a1[j] + bs1[j]);
        wu[(size_t)(base_nb+o1-10)*HW + pix] = g1;
      }
    }
  }
}

// ---------------------------------------------------------------------------
// Kernel D: candidate conv + GRU blend, 4-row tiles + swizzle; packed msg load
// ---------------------------------------------------------------------------
__global__ __launch_bounds__(256, 3)
void k_gru_out(const float* __restrict__ pnn, const float* __restrict__ Wc,
               const float* __restrict__ bc,
               const unsigned* __restrict__ wmsg_p, const float* __restrict__ wrh,
               const float* __restrict__ wu, float* __restrict__ out)
{
  __shared__ __align__(16) unsigned short tl[T6_N];
  __shared__ __align__(16) unsigned short wl[WC_ELEMS];
  const int bi = swz768(blockIdx.x);
  const int n  = bi >> 7;
  const int b  = (bi >> 5) & 3;
  const int y0 = (bi & 31) * 4;
  const int tid = threadIdx.x;

  const int base_nb  = (n*NB+b)*10;
  const int base_nb5 = (n*NB+b)*5;
  const float* rhb  = wrh  + (size_t)base_nb*HW;
  const float* pb   = pnn  + (size_t)base_nb*HW;

  short8_t zz = {0,0,0,0,0,0,0,0};
#pragma unroll
  for (int it=0; it<10; ++it){
    const int e = tid*8 + it*2048;
    if (e < T6_N) *reinterpret_cast<short8_t*>(&tl[e]) = zz;
  }
#pragma unroll
  for (int it=0; it<2; ++it){
    const int e = tid*8 + it*2048;
    if (e < WC_ELEMS) *reinterpret_cast<short8_t*>(&wl[e]) = zz;
  }
  __syncthreads();

  const float* Wn = Wc + n*1800;
#pragma unroll
  for (int it=0; it<4; ++it){
    const int e = tid + it*256;
    if (e < 900){
      int sh = e/100, rem = e - sh*100, o = rem/10, chp = rem - o*10;
      float w0 = Wn[o*180 + (2*chp  )*9 + sh];
      float w1 = Wn[o*180 + (2*chp+1)*9 + sh];
      *reinterpret_cast<unsigned*>(&wl[(sh*16+o)*TCH + 2*chp]) = pk2bf(w0, w1);
    }
  }
#pragma unroll
  for (int it=0; it<30; ++it){
    const int e = tid + it*256;
    int row = e/1280, rem = e - row*1280, chp = rem>>7, x = rem&127;
    int yy = y0 - 1 + row;
    if ((unsigned)yy < 128u){
      unsigned pk;
      if (chp < 5){
        pk = wmsg_p[((size_t)(base_nb5 + chp))*HW + yy*WID + x];
      } else {
        const float* s0 = rhb + (size_t)(2*chp-10)*HW;
        pk = pk2bf(s0[yy*WID + x], s0[HW + yy*WID + x]);
      }
      *reinterpret_cast<unsigned*>(&tl[(row*TROW + x+1)*TCH + 2*chp]) = pk;
    }
  }
  __syncthreads();

  const int l  = tid & 63;
  const int w  = tid >> 6;
  const int lr = l & 15;
  const int lk = l >> 4;

  short8_t wa[9];
#pragma unroll
  for (int sh=0; sh<9; sh++)
    wa[sh] = (lk<3) ? *reinterpret_cast<const short8_t*>(&wl[(sh*16 + lr)*TCH + lk*8]) : zz;

  float bs[4];
#pragma unroll
  for (int j=0;j<4;j++){
    int o = lk*4 + j;
    bs[j] = (o < 10) ? bc[n*10 + o] : 0.f;
  }

  for (int t=0; t<8; ++t){
    const int tile  = w*8 + t;
    const int row_t = tile >> 3;
    const int xloc  = (tile & 7) * 16;

    float4_t a0 = {0.f,0.f,0.f,0.f};
#pragma unroll
    for (int sh=0; sh<9; sh++){
      const int dy = sh/3, dx = sh - dy*3;
      const int addr = ((row_t + dy)*TROW + (xloc + lr + dx))*TCH + lk*8;
      short8_t bf = (lk<3) ? *reinterpret_cast<const short8_t*>(&tl[addr]) : zz;
      a0 = __builtin_amdgcn_mfma_f32_16x16x32_bf16(wa[sh], bf, a0, 0,0,0);
    }

    const int pix = (y0 + row_t)*WID + xloc + lr;
#pragma unroll
    for (int j=0;j<4;j++){
      const int o = lk*4 + j;
      if (o < 10){
        float cand = tanh_(a0[j] + bs[j]);
        float uu = wu[(size_t)(base_nb+o)*HW + pix];
        float hh = pb[(size_t)o*HW + pix];
        out[(size_t)(base_nb+o)*HW + pix] = (1.f-uu)*hh + uu*cand;
      }
    }
  }
}

// ---------------------------------------------------------------------------
extern "C" void kernel_launch(void* const* d_in, const int* in_sizes, int n_in,
                              void* d_out, int out_size, void* d_ws, size_t ws_size,
                              hipStream_t stream)
{
  (void)in_sizes; (void)n_in; (void)out_size; (void)ws_size;
  const float* hn   = (const float*)d_in[1];
  const float* pnn  = (const float*)d_in[2];
  const float* xp   = (const float*)d_in[3];
  const float* Wdau = (const float*)d_in[4];
  const float* bdau = (const float*)d_in[5];
  const float* Wdal = (const float*)d_in[6];
  const float* bdal = (const float*)d_in[7];
  const float* Wd1  = (const float*)d_in[8];
  const float* s1v  = (const float*)d_in[9];
  const float* t1v  = (const float*)d_in[10];
  const float* Wd2  = (const float*)d_in[11];
  const float* s2v  = (const float*)d_in[12];
  const float* t2v  = (const float*)d_in[13];
  const float* Wa0  = (const float*)d_in[14];
  const float* Wa1  = (const float*)d_in[15];
  const float* Wa2  = (const float*)d_in[16];
  const float* Wa3  = (const float*)d_in[17];
  const float* Wa4  = (const float*)d_in[18];
  const float* Wa5  = (const float*)d_in[19];
  const float* batt = (const float*)d_in[20];
  const float* Wp   = (const float*)d_in[21];
  const float* ps   = (const float*)d_in[22];
  const float* pt   = (const float*)d_in[23];
  const float* Wg   = (const float*)d_in[24];
  const float* bg   = (const float*)d_in[25];
  const float* Wc   = (const float*)d_in[26];
  const float* bc   = (const float*)d_in[27];

  float* out = (float*)d_out;
  float* wsf = (float*)d_ws;
  unsigned* ws_msg = (unsigned*)wsf;                 // packed bf16 pairs [6*4*5*HW] u32
  float*    ws_rh  = wsf + 3932160;                  // f32 [6*4*10*HW]
  float*    ws_u   = wsf + 7864320;                  // f32 [6*4*10*HW]

  k_att_dec<<<dim3(1536), dim3(256), 0, stream>>>(hn, pnn, Wdau, bdau, Wdal, bdal,
      Wd1, s1v, t1v, Wd2, s2v, t2v, Wa0, Wa1, Wa2, Wa3, Wa4, Wa5, batt, out, ws_msg);
  k_proj<<<dim3(1024), dim3(256), 0, stream>>>(xp, Wp, ps, pt, (const float*)d_out, ws_msg);
  k_gru_gates<<<dim3(768), dim3(256), 0, stream>>>(pnn, Wg, bg, ws_msg, ws_rh, ws_u);
  k_gru_out<<<dim3(768), dim3(256), 0, stream>>>(pnn, Wc, bc, ws_msg, ws_rh, ws_u, out);
}

// Round 15
// 88.586 us; speedup vs baseline: 1.5171x; 1.1940x over previous
//
#include <hip/hip_runtime.h>
#include <math.h>

#define HW    16384
#define WID   128
#define NB    4
// output section offsets (floats)
#define OFF_U 3932160
#define OFF_L 4259840
#define OFF_F 4456448

// conv tile geometry (ch-interleaved bf16): [6 rows][132 x][24 ch]
#define TCH   24
#define TROW  132
#define T6_N  (6*TROW*TCH)        // 19008 shorts = 38.0 KB
#define WG_ELEMS   (9*32*TCH)     // 6912 shorts  = 13.8 KB
#define WC_ELEMS   (9*16*TCH)     // 3456 shorts  =  6.9 KB

typedef __attribute__((ext_vector_type(8))) short  short8_t;
typedef __attribute__((ext_vector_type(4))) float  float4_t;

__device__ __forceinline__ float sig_(float x)  { return 1.f/(1.f+__expf(-x)); }
__device__ __forceinline__ float tanh_(float x) { float e=__expf(2.f*x); return 1.f - 2.f/(e+1.f); }
// HW packed fp32->bf16 pair (dst.lo = bf16(a), dst.hi = bf16(b))
__device__ __forceinline__ unsigned pk2bf(float a, float b){
  unsigned r;
  asm("v_cvt_pk_bf16_f32 %0, %1, %2" : "=v"(r) : "v"(a), "v"(b));
  return r;
}
__device__ __forceinline__ float bf2f(unsigned short s){
  return __uint_as_float(((unsigned)s) << 16);
}
// XCD-aware bijective swizzles
__device__ __forceinline__ int swz1536(int bi){ return (bi & 7)*192 + (bi >> 3); }
__device__ __forceinline__ int swz768 (int bi){ return (bi & 7)*96  + (bi >> 3); }

// ---------------------------------------------------------------------------
// Kernel A: node-split (grid 1536) + XCD swizzle.  wmsg PACKED bf16 pairs.
// ---------------------------------------------------------------------------
__global__ __launch_bounds__(256)
void k_att_dec(const float* __restrict__ hn, const float* __restrict__ pnn,
               const float* __restrict__ Wdau, const float* __restrict__ bdau,
               const float* __restrict__ Wdal, const float* __restrict__ bdal,
               const float* __restrict__ Wd1, const float* __restrict__ s1v, const float* __restrict__ t1v,
               const float* __restrict__ Wd2, const float* __restrict__ s2v, const float* __restrict__ t2v,
               const float* __restrict__ Wa0, const float* __restrict__ Wa1, const float* __restrict__ Wa2,
               const float* __restrict__ Wa3, const float* __restrict__ Wa4, const float* __restrict__ Wa5,
               const float* __restrict__ batt,
               float* __restrict__ out, unsigned* __restrict__ wmsg_p)
{
  const int bi  = swz1536(blockIdx.x);
  const int n   = bi >> 8;
  const int g   = (bi & 255)*256 + threadIdx.x;
  const int b   = g >> 14;
  const int pix = g & 16383;

  float h[10];
  float a;
  if (n < 4){
#pragma unroll
    for (int c=0;c<10;c++) h[c] = hn[(b*10+c)*HW + pix];
    float v[5]; float mx = -1e30f;
#pragma unroll
    for (int o=0;o<5;o++){
      float t = bdau[o];
#pragma unroll
      for (int c=0;c<10;c++) t += Wdau[o*10+c]*h[c];
      if (n==0) out[OFF_U + (b*5+o)*HW + pix] = t;
      v[o]=t; mx = fmaxf(mx,t);
    }
    float s=0.f;
#pragma unroll
    for (int o=0;o<5;o++){ v[o]=__expf(v[o]-mx); s+=v[o]; }
    a = v[n+1]/s;
  } else {
#pragma unroll
    for (int c=0;c<10;c++) h[c] = hn[((NB+b)*10+c)*HW + pix];
    float v[3]; float mx = -1e30f;
#pragma unroll
    for (int o=0;o<3;o++){
      float t = bdal[o];
#pragma unroll
      for (int c=0;c<10;c++) t += Wdal[o*10+c]*h[c];
      if (n==4) out[OFF_L + (b*3+o)*HW + pix] = t;
      v[o]=t; mx = fmaxf(mx,t);
    }
    float s=0.f;
#pragma unroll
    for (int o=0;o<3;o++){ v[o]=__expf(v[o]-mx); s+=v[o]; }
    a = v[n-3]/s;
  }

  float child[10];
#pragma unroll
  for (int c=0;c<10;c++) child[c] = pnn[((n*NB+b)*10+c)*HW + pix];

  float af = batt[n];
  if (n==0){
#pragma unroll
    for (int c=0;c<10;c++) af += Wa0[c]*pnn[((1*NB+b)*10+c)*HW+pix];
  } else if (n==1){
#pragma unroll
    for (int c=0;c<10;c++){
      af += Wa1[c]   *pnn[((0*NB+b)*10+c)*HW+pix];
      af += Wa1[10+c]*pnn[((2*NB+b)*10+c)*HW+pix];
      af += Wa1[20+c]*pnn[((3*NB+b)*10+c)*HW+pix];
      af += Wa1[30+c]*pnn[((4*NB+b)*10+c)*HW+pix];
    }
  } else if (n==2){
#pragma unroll
    for (int c=0;c<10;c++) af += Wa2[c]*pnn[((1*NB+b)*10+c)*HW+pix];
  } else if (n==3){
#pragma unroll
    for (int c=0;c<10;c++) af += Wa3[c]*pnn[((1*NB+b)*10+c)*HW+pix];
  } else if (n==4){
#pragma unroll
    for (int c=0;c<10;c++){
      af += Wa4[c]   *pnn[((1*NB+b)*10+c)*HW+pix];
      af += Wa4[10+c]*pnn[((5*NB+b)*10+c)*HW+pix];
    }
  } else {
#pragma unroll
    for (int c=0;c<10;c++) af += Wa5[c]*pnn[((4*NB+b)*10+c)*HW+pix];
  }
  out[OFF_F + (n*NB+b)*HW + pix] = sig_(af);

  float x20[20];
#pragma unroll
  for (int c=0;c<10;c++){ x20[c]=h[c]*a; x20[10+c]=child[c]; }
  float h20[20];
#pragma unroll
  for (int o=0;o<20;o++){
    float acc=0.f;
#pragma unroll
    for (int c=0;c<20;c++) acc += Wd1[o*20+c]*x20[c];
    h20[o] = fmaxf(acc*s1v[o]+t1v[o], 0.f);
  }
  float msg10[10];
#pragma unroll
  for (int o=0;o<10;o++){
    float acc=0.f;
#pragma unroll
    for (int c=0;c<20;c++) acc += Wd2[o*20+c]*h20[c];
    msg10[o] = fmaxf(acc*s2v[o]+t2v[o], 0.f);
  }
#pragma unroll
  for (int p=0;p<5;p++)
    wmsg_p[((size_t)((n*NB+b)*5 + p))*HW + pix] = pk2bf(msg10[2*p], msg10[2*p+1]);
}

// ---------------------------------------------------------------------------
// Kernel B: projection GEMM v3 with packed-bf16 RMW epilogue (unchanged r14)
// ---------------------------------------------------------------------------
__global__ __launch_bounds__(256, 2)
void k_proj(const float* __restrict__ xp, const float* __restrict__ Wp,
            const float* __restrict__ ps, const float* __restrict__ pt,
            const float* __restrict__ outf, unsigned* __restrict__ wmsg_p)
{
  __shared__ __align__(16) unsigned short wlds[64*264];
  const int tid = threadIdx.x;

#pragma unroll
  for (int it=0; it<16; ++it){
    const int e = tid + it*256;
    const int row = e >> 6, q = e & 63;
    uint2 pk; pk.x = 0u; pk.y = 0u;
    if (row < 60){
      const float s = ps[row];
      float4 wv = *reinterpret_cast<const float4*>(Wp + row*256 + q*4);
      pk.x = pk2bf(wv.x*s, wv.y*s);
      pk.y = pk2bf(wv.z*s, wv.w*s);
    }
    *reinterpret_cast<uint2*>(&wlds[row*264 + q*4]) = pk;
  }
  __syncthreads();

  const int l  = tid & 63;
  const int w  = tid >> 6;
  const int lr = l & 15;
  const int lk = l >> 4;

  const int tile = blockIdx.x*4 + w;
  const int P    = tile*16;
  const int b    = P >> 14;
  const int pixb = P & 16383;
  const int px   = pixb + lr;

  const float* xb = xp + (size_t)(b*256)*HW + px;
  float v[64];
#pragma unroll
  for (int ks=0; ks<8; ++ks)
#pragma unroll
    for (int j=0; j<8; ++j)
      v[ks*8+j] = xb[(size_t)(ks*32 + lk*8 + j)*HW];

  short8_t bf[8];
#pragma unroll
  for (int ks=0; ks<8; ++ks){
    union { short8_t s; unsigned u[4]; } bu;
#pragma unroll
    for (int jp=0; jp<4; ++jp)
      bu.u[jp] = pk2bf(v[ks*8+2*jp], v[ks*8+2*jp+1]);
    bf[ks] = bu.s;
  }

  float4_t acc[4];
#pragma unroll
  for (int nf=0;nf<4;nf++){ acc[nf][0]=0.f; acc[nf][1]=0.f; acc[nf][2]=0.f; acc[nf][3]=0.f; }

#pragma unroll
  for (int ks=0; ks<8; ++ks){
#pragma unroll
    for (int nf=0; nf<4; ++nf){
      short8_t wa = *reinterpret_cast<const short8_t*>(&wlds[(nf*16+lr)*264 + ks*32 + lk*8]);
      acc[nf] = __builtin_amdgcn_mfma_f32_16x16x32_bf16(wa, bf[ks], acc[nf], 0,0,0);
    }
  }

#pragma unroll
  for (int nf=0;nf<4;nf++){
#pragma unroll
    for (int jp=0;jp<2;jp++){
      const int row0 = nf*16 + lk*4 + 2*jp;       // even
      if (row0 < 60){
        const unsigned nn = (unsigned)row0 / 10u;
        const int o = row0 - (int)nn*10;          // even, o+1 same node
        float att = outf[OFF_F + (nn*NB+b)*HW + pixb + lr];
        float f   = 2.f - att;
        float v0 = fmaxf(f*acc[nf][2*jp]   + pt[row0],   0.f);
        float v1 = fmaxf(f*acc[nf][2*jp+1] + pt[row0+1], 0.f);
        size_t idx = ((size_t)((nn*NB+b)*5 + (o>>1)))*HW + pixb + lr;
        unsigned old = wmsg_p[idx];
        float d0 = bf2f((unsigned short)(old & 0xffffu)) + v0;
        float d1 = bf2f((unsigned short)(old >> 16))     + v1;
        wmsg_p[idx] = pk2bf(d0, d1);
      }
    }
  }
}

// ---------------------------------------------------------------------------
// Kernel C: GRU gates conv, 4-row tiles + XCD swizzle.  msg staged via packed
// u32 load; rh/u now WRITTEN PACKED as bf16 pairs ([nb][5][HW] u32 each).
// ---------------------------------------------------------------------------
__global__ __launch_bounds__(256, 3)
void k_gru_gates(const float* __restrict__ pnn, const float* __restrict__ Wg,
                 const float* __restrict__ bg,
                 const unsigned* __restrict__ wmsg_p, unsigned* __restrict__ wrh_p,
                 unsigned* __restrict__ wu_p)
{
  __shared__ __align__(16) unsigned short tl[T6_N];
  __shared__ __align__(16) unsigned short wl[WG_ELEMS];
  const int bi = swz768(blockIdx.x);
  const int n  = bi >> 7;
  const int b  = (bi >> 5) & 3;
  const int y0 = (bi & 31) * 4;
  const int tid = threadIdx.x;

  const int base_nb  = (n*NB+b)*10;
  const int base_nb5 = (n*NB+b)*5;
  const float* pb = pnn + (size_t)base_nb*HW;

  short8_t zz = {0,0,0,0,0,0,0,0};
#pragma unroll
  for (int it=0; it<10; ++it){
    const int e = tid*8 + it*2048;
    if (e < T6_N) *reinterpret_cast<short8_t*>(&tl[e]) = zz;
  }
#pragma unroll
  for (int it=0; it<4; ++it){
    const int e = tid*8 + it*2048;
    if (e < WG_ELEMS) *reinterpret_cast<short8_t*>(&wl[e]) = zz;
  }
  __syncthreads();

  const float* Wn = Wg + n*3600;
#pragma unroll
  for (int it=0; it<8; ++it){
    const int e = tid + it*256;
    if (e < 1800){
      int sh = e/200, rem = e - sh*200, o = rem/10, chp = rem - o*10;
      float w0 = Wn[o*180 + (2*chp  )*9 + sh];
      float w1 = Wn[o*180 + (2*chp+1)*9 + sh];
      *reinterpret_cast<unsigned*>(&wl[(sh*32+o)*TCH + 2*chp]) = pk2bf(w0, w1);
    }
  }
  // input tile: 6 rows x 10 chp x 128  (chp<5: packed msg; chp>=5: pnn f32)
#pragma unroll
  for (int it=0; it<30; ++it){
    const int e = tid + it*256;           // e < 7680 always
    int row = e/1280, rem = e - row*1280, chp = rem>>7, x = rem&127;
    int yy = y0 - 1 + row;
    if ((unsigned)yy < 128u){
      unsigned pk;
      if (chp < 5){
        pk = wmsg_p[((size_t)(base_nb5 + chp))*HW + yy*WID + x];
      } else {
        const float* s0 = pb + (size_t)(2*chp-10)*HW;
        pk = pk2bf(s0[yy*WID + x], s0[HW + yy*WID + x]);
      }
      *reinterpret_cast<unsigned*>(&tl[(row*TROW + x+1)*TCH + 2*chp]) = pk;
    }
  }
  __syncthreads();

  const int l  = tid & 63;
  const int w  = tid >> 6;
  const int lr = l & 15;
  const int lk = l >> 4;

  short8_t wa0[9], wa1[9];
#pragma unroll
  for (int sh=0; sh<9; sh++){
    wa0[sh] = (lk<3) ? *reinterpret_cast<const short8_t*>(&wl[(sh*32 +      lr)*TCH + lk*8]) : zz;
    wa1[sh] = (lk<3) ? *reinterpret_cast<const short8_t*>(&wl[(sh*32 + 16 + lr)*TCH + lk*8]) : zz;
  }
  float bs0[4], bs1[4];
#pragma unroll
  for (int j=0;j<4;j++){
    int o = lk*4 + j;
    bs0[j] = bg[n*20 + o];
    int o1 = 16 + lk*4 + j;
    bs1[j] = (o1 < 20) ? bg[n*20 + o1] : 0.f;
  }

  for (int t=0; t<8; ++t){
    const int tile  = w*8 + t;
    const int row_t = tile >> 3;          // 0..3
    const int xloc  = (tile & 7) * 16;

    float4_t a0 = {0.f,0.f,0.f,0.f}, a1 = {0.f,0.f,0.f,0.f};
#pragma unroll
    for (int sh=0; sh<9; sh++){
      const int dy = sh/3, dx = sh - dy*3;
      const int addr = ((row_t + dy)*TROW + (xloc + lr + dx))*TCH + lk*8;
      short8_t bf = (lk<3) ? *reinterpret_cast<const short8_t*>(&tl[addr]) : zz;
      a0 = __builtin_amdgcn_mfma_f32_16x16x32_bf16(wa0[sh], bf, a0, 0,0,0);
      a1 = __builtin_amdgcn_mfma_f32_16x16x32_bf16(wa1[sh], bf, a1, 0,0,0);
    }

    const int pix = (y0 + row_t)*WID + xloc + lr;
#pragma unroll
    for (int jp=0; jp<2; ++jp){
      const int j0 = 2*jp;
      const int o  = lk*4 + j0;
      float g0 = sig_(a0[j0]   + bs0[j0]);
      float g1 = sig_(a0[j0+1] + bs0[j0+1]);
      if (o < 10){
        float h0 = pb[(size_t)o*HW + pix];
        float h1 = pb[(size_t)(o+1)*HW + pix];
        wrh_p[((size_t)(base_nb5 + (o>>1)))*HW + pix] = pk2bf(g0*h0, g1*h1);
      } else {
        wu_p[((size_t)(base_nb5 + ((o-10)>>1)))*HW + pix] = pk2bf(g0, g1);
      }
    }
    if (lk == 0){
#pragma unroll
      for (int jp=0; jp<2; ++jp){
        const int j0 = 2*jp;
        const int o1 = 16 + j0;                  // u ch 6..9
        float g0 = sig_(a1[j0]   + bs1[j0]);
        float g1 = sig_(a1[j0+1] + bs1[j0+1]);
        wu_p[((size_t)(base_nb5 + ((o1-10)>>1)))*HW + pix] = pk2bf(g0, g1);
      }
    }
  }
}

// ---------------------------------------------------------------------------
// Kernel D: candidate conv + GRU blend; msg AND rh staged via single packed
// u32 loads; u unpacked from packed bf16 in the blend.
// ---------------------------------------------------------------------------
__global__ __launch_bounds__(256, 3)
void k_gru_out(const float* __restrict__ pnn, const float* __restrict__ Wc,
               const float* __restrict__ bc,
               const unsigned* __restrict__ wmsg_p, const unsigned* __restrict__ wrh_p,
               const unsigned* __restrict__ wu_p, float* __restrict__ out)
{
  __shared__ __align__(16) unsigned short tl[T6_N];
  __shared__ __align__(16) unsigned short wl[WC_ELEMS];
  const int bi = swz768(blockIdx.x);
  const int n  = bi >> 7;
  const int b  = (bi >> 5) & 3;
  const int y0 = (bi & 31) * 4;
  const int tid = threadIdx.x;

  const int base_nb  = (n*NB+b)*10;
  const int base_nb5 = (n*NB+b)*5;
  const float* pb = pnn + (size_t)base_nb*HW;

  short8_t zz = {0,0,0,0,0,0,0,0};
#pragma unroll
  for (int it=0; it<10; ++it){
    const int e = tid*8 + it*2048;
    if (e < T6_N) *reinterpret_cast<short8_t*>(&tl[e]) = zz;
  }
#pragma unroll
  for (int it=0; it<2; ++it){
    const int e = tid*8 + it*2048;
    if (e < WC_ELEMS) *reinterpret_cast<short8_t*>(&wl[e]) = zz;
  }
  __syncthreads();

  const float* Wn = Wc + n*1800;
#pragma unroll
  for (int it=0; it<4; ++it){
    const int e = tid + it*256;
    if (e < 900){
      int sh = e/100, rem = e - sh*100, o = rem/10, chp = rem - o*10;
      float w0 = Wn[o*180 + (2*chp  )*9 + sh];
      float w1 = Wn[o*180 + (2*chp+1)*9 + sh];
      *reinterpret_cast<unsigned*>(&wl[(sh*16+o)*TCH + 2*chp]) = pk2bf(w0, w1);
    }
  }
#pragma unroll
  for (int it=0; it<30; ++it){
    const int e = tid + it*256;
    int row = e/1280, rem = e - row*1280, chp = rem>>7, x = rem&127;
    int yy = y0 - 1 + row;
    if ((unsigned)yy < 128u){
      unsigned pk;
      if (chp < 5){
        pk = wmsg_p[((size_t)(base_nb5 + chp))*HW + yy*WID + x];
      } else {
        pk = wrh_p[((size_t)(base_nb5 + (chp-5)))*HW + yy*WID + x];
      }
      *reinterpret_cast<unsigned*>(&tl[(row*TROW + x+1)*TCH + 2*chp]) = pk;
    }
  }
  __syncthreads();

  const int l  = tid & 63;
  const int w  = tid >> 6;
  const int lr = l & 15;
  const int lk = l >> 4;

  short8_t wa[9];
#pragma unroll
  for (int sh=0; sh<9; sh++)
    wa[sh] = (lk<3) ? *reinterpret_cast<const short8_t*>(&wl[(sh*16 + lr)*TCH + lk*8]) : zz;

  float bs[4];
#pragma unroll
  for (int j=0;j<4;j++){
    int o = lk*4 + j;
    bs[j] = (o < 10) ? bc[n*10 + o] : 0.f;
  }

  for (int t=0; t<8; ++t){
    const int tile  = w*8 + t;
    const int row_t = tile >> 3;
    const int xloc  = (tile & 7) * 16;

    float4_t a0 = {0.f,0.f,0.f,0.f};
#pragma unroll
    for (int sh=0; sh<9; sh++){
      const int dy = sh/3, dx = sh - dy*3;
      const int addr = ((row_t + dy)*TROW + (xloc + lr + dx))*TCH + lk*8;
      short8_t bf = (lk<3) ? *reinterpret_cast<const short8_t*>(&tl[addr]) : zz;
      a0 = __builtin_amdgcn_mfma_f32_16x16x32_bf16(wa[sh], bf, a0, 0,0,0);
    }

    const int pix = (y0 + row_t)*WID + xloc + lr;
#pragma unroll
    for (int jp=0; jp<2; ++jp){
      const int j0 = 2*jp;
      const int o  = lk*4 + j0;
      if (o < 10){
        unsigned up = wu_p[((size_t)(base_nb5 + (o>>1)))*HW + pix];
        float u0 = bf2f((unsigned short)(up & 0xffffu));
        float u1 = bf2f((unsigned short)(up >> 16));
        float h0 = pb[(size_t)o*HW + pix];
        float h1 = pb[(size_t)(o+1)*HW + pix];
        float c0 = tanh_(a0[j0]   + bs[j0]);
        float c1 = tanh_(a0[j0+1] + bs[j0+1]);
        out[(size_t)(base_nb+o  )*HW + pix] = (1.f-u0)*h0 + u0*c0;
        out[(size_t)(base_nb+o+1)*HW + pix] = (1.f-u1)*h1 + u1*c1;
      }
    }
  }
}

// ---------------------------------------------------------------------------
extern "C" void kernel_launch(void* const* d_in, const int* in_sizes, int n_in,
                              void* d_out, int out_size, void* d_ws, size_t ws_size,
                              hipStream_t stream)
{
  (void)in_sizes; (void)n_in; (void)out_size; (void)ws_size;
  const float* hn   = (const float*)d_in[1];
  const float* pnn  = (const float*)d_in[2];
  const float* xp   = (const float*)d_in[3];
  const float* Wdau = (const float*)d_in[4];
  const float* bdau = (const float*)d_in[5];
  const float* Wdal = (const float*)d_in[6];
  const float* bdal = (const float*)d_in[7];
  const float* Wd1  = (const float*)d_in[8];
  const float* s1v  = (const float*)d_in[9];
  const float* t1v  = (const float*)d_in[10];
  const float* Wd2  = (const float*)d_in[11];
  const float* s2v  = (const float*)d_in[12];
  const float* t2v  = (const float*)d_in[13];
  const float* Wa0  = (const float*)d_in[14];
  const float* Wa1  = (const float*)d_in[15];
  const float* Wa2  = (const float*)d_in[16];
  const float* Wa3  = (const float*)d_in[17];
  const float* Wa4  = (const float*)d_in[18];
  const float* Wa5  = (const float*)d_in[19];
  const float* batt = (const float*)d_in[20];
  const float* Wp   = (const float*)d_in[21];
  const float* ps   = (const float*)d_in[22];
  const float* pt   = (const float*)d_in[23];
  const float* Wg   = (const float*)d_in[24];
  const float* bg   = (const float*)d_in[25];
  const float* Wc   = (const float*)d_in[26];
  const float* bc   = (const float*)d_in[27];

  float* out = (float*)d_out;
  float* wsf = (float*)d_ws;
  unsigned* ws_msg = (unsigned*)wsf;                 // packed bf16 pairs [6*4*5*HW] u32
  unsigned* ws_rh  = (unsigned*)(wsf + 1966080);     // packed bf16 pairs [6*4*5*HW] u32
  unsigned* ws_u   = (unsigned*)(wsf + 3932160);     // packed bf16 pairs [6*4*5*HW] u32

  k_att_dec<<<dim3(1536), dim3(256), 0, stream>>>(hn, pnn, Wdau, bdau, Wdal, bdal,
      Wd1, s1v, t1v, Wd2, s2v, t2v, Wa0, Wa1, Wa2, Wa3, Wa4, Wa5, batt, out, ws_msg);
  k_proj<<<dim3(1024), dim3(256), 0, stream>>>(xp, Wp, ps, pt, (const float*)d_out, ws_msg);
  k_gru_gates<<<dim3(768), dim3(256), 0, stream>>>(pnn, Wg, bg, ws_msg, ws_rh, ws_u);
  k_gru_out<<<dim3(768), dim3(256), 0, stream>>>(pnn, Wc, bc, ws_msg, ws_rh, ws_u, out);
}

// Round 16
// 85.271 us; speedup vs baseline: 1.5761x; 1.0389x over previous
//
#include <hip/hip_runtime.h>
#include <math.h>

#define HW    16384
#define WID   128
#define NB    4
// output section offsets (floats)
#define OFF_U 3932160
#define OFF_L 4259840
#define OFF_F 4456448

// conv tile geometry (ch-interleaved bf16): [6 rows][132 x][24 ch]
#define TCH   24
#define TROW  132
#define T6_N  (6*TROW*TCH)        // 19008 shorts = 38.0 KB
#define WG_ELEMS   (9*32*TCH)     // 6912 shorts  = 13.8 KB
#define WC_ELEMS   (9*16*TCH)     // 3456 shorts  =  6.9 KB

typedef __attribute__((ext_vector_type(8))) short  short8_t;
typedef __attribute__((ext_vector_type(4))) float  float4_t;

__device__ __forceinline__ float sig_(float x)  { return 1.f/(1.f+__expf(-x)); }
__device__ __forceinline__ float tanh_(float x) { float e=__expf(2.f*x); return 1.f - 2.f/(e+1.f); }
// HW packed fp32->bf16 pair (dst.lo = bf16(a), dst.hi = bf16(b))
__device__ __forceinline__ unsigned pk2bf(float a, float b){
  unsigned r;
  asm("v_cvt_pk_bf16_f32 %0, %1, %2" : "=v"(r) : "v"(a), "v"(b));
  return r;
}
__device__ __forceinline__ float bf2f(unsigned short s){
  return __uint_as_float(((unsigned)s) << 16);
}
// XCD-aware bijective swizzles
__device__ __forceinline__ int swz1536(int bi){ return (bi & 7)*192 + (bi >> 3); }
__device__ __forceinline__ int swz768 (int bi){ return (bi & 7)*96  + (bi >> 3); }

// ---------------------------------------------------------------------------
// Kernel A v2: node-split + XCD swizzle; relation as 2-stage MFMA GEMM.
// Per block: 256 px (one b).  x20 staged [256px][24ch] bf16; W1/W2 s-folded
// bf16 in LDS; h20 relu'd + re-staged; msg packed bf16 pairs out.
// Softmax att / Fdep / out-map writes stay per-thread VALU.
// ---------------------------------------------------------------------------
__global__ __launch_bounds__(256)
void k_att_dec(const float* __restrict__ hn, const float* __restrict__ pnn,
               const float* __restrict__ Wdau, const float* __restrict__ bdau,
               const float* __restrict__ Wdal, const float* __restrict__ bdal,
               const float* __restrict__ Wd1, const float* __restrict__ s1v, const float* __restrict__ t1v,
               const float* __restrict__ Wd2, const float* __restrict__ s2v, const float* __restrict__ t2v,
               const float* __restrict__ Wa0, const float* __restrict__ Wa1, const float* __restrict__ Wa2,
               const float* __restrict__ Wa3, const float* __restrict__ Wa4, const float* __restrict__ Wa5,
               const float* __restrict__ batt,
               float* __restrict__ out, unsigned* __restrict__ wmsg_p)
{
  __shared__ __align__(16) unsigned short xl [256*TCH];   // 12.3 KB
  __shared__ __align__(16) unsigned short hl [256*TCH];   // 12.3 KB
  __shared__ __align__(16) unsigned short wl1[32*TCH];    // 1.5 KB
  __shared__ __align__(16) unsigned short wl2[16*TCH];    // 0.75 KB

  const int bi    = swz1536(blockIdx.x);
  const int n     = bi >> 8;
  const int chunk = bi & 255;
  const int b     = chunk >> 6;
  const int pixbase = (chunk & 63) * 256;
  const int tid   = threadIdx.x;
  const int pix   = pixbase + tid;

  short8_t zz = {0,0,0,0,0,0,0,0};
  // zero LDS (pads)
#pragma unroll
  for (int it=0; it<3; ++it) *reinterpret_cast<short8_t*>(&xl[tid*8 + it*2048]) = zz;
#pragma unroll
  for (int it=0; it<3; ++it) *reinterpret_cast<short8_t*>(&hl[tid*8 + it*2048]) = zz;
  if (tid < 96)  *reinterpret_cast<short8_t*>(&wl1[tid*8]) = zz;
  if (tid < 48)  *reinterpret_cast<short8_t*>(&wl2[tid*8]) = zz;
  __syncthreads();

  // stage s-folded relation weights
  if (tid < 200){
    int o = tid/10, chp = tid - o*10;
    float s = s1v[o];
    *reinterpret_cast<unsigned*>(&wl1[o*TCH + 2*chp]) =
        pk2bf(Wd1[o*20 + 2*chp]*s, Wd1[o*20 + 2*chp+1]*s);
  } else if (tid < 300){
    int e = tid - 200;
    int o = e/10, chp = e - o*10;
    float s = s2v[o];
    *reinterpret_cast<unsigned*>(&wl2[o*TCH + 2*chp]) =
        pk2bf(Wd2[o*20 + 2*chp]*s, Wd2[o*20 + 2*chp+1]*s);
  }

  // ---- per-thread: softmax att, Fdep, out-maps, build + stage x20 ----
  float h[10];
  float a;
  if (n < 4){
#pragma unroll
    for (int c=0;c<10;c++) h[c] = hn[(b*10+c)*HW + pix];
    float v[5]; float mx = -1e30f;
#pragma unroll
    for (int o=0;o<5;o++){
      float t = bdau[o];
#pragma unroll
      for (int c=0;c<10;c++) t += Wdau[o*10+c]*h[c];
      if (n==0) out[OFF_U + (b*5+o)*HW + pix] = t;
      v[o]=t; mx = fmaxf(mx,t);
    }
    float s=0.f;
#pragma unroll
    for (int o=0;o<5;o++){ v[o]=__expf(v[o]-mx); s+=v[o]; }
    a = v[n+1]/s;
  } else {
#pragma unroll
    for (int c=0;c<10;c++) h[c] = hn[((NB+b)*10+c)*HW + pix];
    float v[3]; float mx = -1e30f;
#pragma unroll
    for (int o=0;o<3;o++){
      float t = bdal[o];
#pragma unroll
      for (int c=0;c<10;c++) t += Wdal[o*10+c]*h[c];
      if (n==4) out[OFF_L + (b*3+o)*HW + pix] = t;
      v[o]=t; mx = fmaxf(mx,t);
    }
    float s=0.f;
#pragma unroll
    for (int o=0;o<3;o++){ v[o]=__expf(v[o]-mx); s+=v[o]; }
    a = v[n-3]/s;
  }

  float child[10];
#pragma unroll
  for (int c=0;c<10;c++) child[c] = pnn[((n*NB+b)*10+c)*HW + pix];

  float af = batt[n];
  if (n==0){
#pragma unroll
    for (int c=0;c<10;c++) af += Wa0[c]*pnn[((1*NB+b)*10+c)*HW+pix];
  } else if (n==1){
#pragma unroll
    for (int c=0;c<10;c++){
      af += Wa1[c]   *pnn[((0*NB+b)*10+c)*HW+pix];
      af += Wa1[10+c]*pnn[((2*NB+b)*10+c)*HW+pix];
      af += Wa1[20+c]*pnn[((3*NB+b)*10+c)*HW+pix];
      af += Wa1[30+c]*pnn[((4*NB+b)*10+c)*HW+pix];
    }
  } else if (n==2){
#pragma unroll
    for (int c=0;c<10;c++) af += Wa2[c]*pnn[((1*NB+b)*10+c)*HW+pix];
  } else if (n==3){
#pragma unroll
    for (int c=0;c<10;c++) af += Wa3[c]*pnn[((1*NB+b)*10+c)*HW+pix];
  } else if (n==4){
#pragma unroll
    for (int c=0;c<10;c++){
      af += Wa4[c]   *pnn[((1*NB+b)*10+c)*HW+pix];
      af += Wa4[10+c]*pnn[((5*NB+b)*10+c)*HW+pix];
    }
  } else {
#pragma unroll
    for (int c=0;c<10;c++) af += Wa5[c]*pnn[((4*NB+b)*10+c)*HW+pix];
  }
  out[OFF_F + (n*NB+b)*HW + pix] = sig_(af);

  // x20 = [h*a (10), child (10)] -> xl[tid][ch] bf16 pairs
#pragma unroll
  for (int p=0;p<5;p++)
    *reinterpret_cast<unsigned*>(&xl[tid*TCH + 2*p])    = pk2bf(h[2*p]*a, h[2*p+1]*a);
#pragma unroll
  for (int p=0;p<5;p++)
    *reinterpret_cast<unsigned*>(&xl[tid*TCH + 10 + 2*p]) = pk2bf(child[2*p], child[2*p+1]);
  __syncthreads();

  // ---- MFMA stage 1: h20 = relu(W1s . x20 + t1) ----
  const int l  = tid & 63;
  const int w  = tid >> 6;
  const int lr = l & 15;
  const int lk = l >> 4;

  short8_t wa0 = (lk<3) ? *reinterpret_cast<const short8_t*>(&wl1[lr*TCH      + lk*8]) : zz;
  short8_t wa1 = (lk<3) ? *reinterpret_cast<const short8_t*>(&wl1[(16+lr)*TCH + lk*8]) : zz;
  float t1a[4], t1b[4];
#pragma unroll
  for (int j=0;j<4;j++){
    t1a[j] = t1v[lk*4 + j];
    int o1 = 16 + lk*4 + j;
    t1b[j] = (o1 < 20) ? t1v[o1] : 0.f;
  }

#pragma unroll
  for (int t=0; t<4; ++t){
    const int tile = w*4 + t;
    short8_t bf = (lk<3) ? *reinterpret_cast<const short8_t*>(&xl[(tile*16+lr)*TCH + lk*8]) : zz;
    float4_t a0 = {0.f,0.f,0.f,0.f}, a1 = {0.f,0.f,0.f,0.f};
    a0 = __builtin_amdgcn_mfma_f32_16x16x32_bf16(wa0, bf, a0, 0,0,0);
    a1 = __builtin_amdgcn_mfma_f32_16x16x32_bf16(wa1, bf, a1, 0,0,0);
    const int rowb = (tile*16+lr)*TCH;
#pragma unroll
    for (int jp=0; jp<2; ++jp){
      float v0 = fmaxf(a0[2*jp]   + t1a[2*jp],   0.f);
      float v1 = fmaxf(a0[2*jp+1] + t1a[2*jp+1], 0.f);
      *reinterpret_cast<unsigned*>(&hl[rowb + lk*4 + 2*jp]) = pk2bf(v0, v1);
    }
    if (lk == 0){
#pragma unroll
      for (int jp=0; jp<2; ++jp){
        float v0 = fmaxf(a1[2*jp]   + t1b[2*jp],   0.f);
        float v1 = fmaxf(a1[2*jp+1] + t1b[2*jp+1], 0.f);
        *reinterpret_cast<unsigned*>(&hl[rowb + 16 + 2*jp]) = pk2bf(v0, v1);
      }
    }
  }
  __syncthreads();

  // ---- MFMA stage 2: msg = relu(W2s . h20 + t2) -> packed wmsg ----
  short8_t wa2 = (lk<3) ? *reinterpret_cast<const short8_t*>(&wl2[lr*TCH + lk*8]) : zz;
  float t2a[4];
#pragma unroll
  for (int j=0;j<4;j++){
    int o = lk*4 + j;
    t2a[j] = (o < 10) ? t2v[o] : 0.f;
  }

#pragma unroll
  for (int t=0; t<4; ++t){
    const int tile = w*4 + t;
    short8_t bf = (lk<3) ? *reinterpret_cast<const short8_t*>(&hl[(tile*16+lr)*TCH + lk*8]) : zz;
    float4_t c = {0.f,0.f,0.f,0.f};
    c = __builtin_amdgcn_mfma_f32_16x16x32_bf16(wa2, bf, c, 0,0,0);
    const int pixT = pixbase + tile*16 + lr;
#pragma unroll
    for (int jp=0; jp<2; ++jp){
      const int o0 = lk*4 + 2*jp;
      if (o0 < 10){
        float v0 = fmaxf(c[2*jp]   + t2a[2*jp],   0.f);
        float v1 = fmaxf(c[2*jp+1] + t2a[2*jp+1], 0.f);
        wmsg_p[((size_t)((n*NB+b)*5 + (o0>>1)))*HW + pixT] = pk2bf(v0, v1);
      }
    }
  }
}

// ---------------------------------------------------------------------------
// Kernel B: projection GEMM v3 with packed-bf16 RMW epilogue (unchanged r15)
// ---------------------------------------------------------------------------
__global__ __launch_bounds__(256, 2)
void k_proj(const float* __restrict__ xp, const float* __restrict__ Wp,
            const float* __restrict__ ps, const float* __restrict__ pt,
            const float* __restrict__ outf, unsigned* __restrict__ wmsg_p)
{
  __shared__ __align__(16) unsigned short wlds[64*264];
  const int tid = threadIdx.x;

#pragma unroll
  for (int it=0; it<16; ++it){
    const int e = tid + it*256;
    const int row = e >> 6, q = e & 63;
    uint2 pk; pk.x = 0u; pk.y = 0u;
    if (row < 60){
      const float s = ps[row];
      float4 wv = *reinterpret_cast<const float4*>(Wp + row*256 + q*4);
      pk.x = pk2bf(wv.x*s, wv.y*s);
      pk.y = pk2bf(wv.z*s, wv.w*s);
    }
    *reinterpret_cast<uint2*>(&wlds[row*264 + q*4]) = pk;
  }
  __syncthreads();

  const int l  = tid & 63;
  const int w  = tid >> 6;
  const int lr = l & 15;
  const int lk = l >> 4;

  const int tile = blockIdx.x*4 + w;
  const int P    = tile*16;
  const int b    = P >> 14;
  const int pixb = P & 16383;
  const int px   = pixb + lr;

  const float* xb = xp + (size_t)(b*256)*HW + px;
  float v[64];
#pragma unroll
  for (int ks=0; ks<8; ++ks)
#pragma unroll
    for (int j=0; j<8; ++j)
      v[ks*8+j] = xb[(size_t)(ks*32 + lk*8 + j)*HW];

  short8_t bf[8];
#pragma unroll
  for (int ks=0; ks<8; ++ks){
    union { short8_t s; unsigned u[4]; } bu;
#pragma unroll
    for (int jp=0; jp<4; ++jp)
      bu.u[jp] = pk2bf(v[ks*8+2*jp], v[ks*8+2*jp+1]);
    bf[ks] = bu.s;
  }

  float4_t acc[4];
#pragma unroll
  for (int nf=0;nf<4;nf++){ acc[nf][0]=0.f; acc[nf][1]=0.f; acc[nf][2]=0.f; acc[nf][3]=0.f; }

#pragma unroll
  for (int ks=0; ks<8; ++ks){
#pragma unroll
    for (int nf=0; nf<4; ++nf){
      short8_t wa = *reinterpret_cast<const short8_t*>(&wlds[(nf*16+lr)*264 + ks*32 + lk*8]);
      acc[nf] = __builtin_amdgcn_mfma_f32_16x16x32_bf16(wa, bf[ks], acc[nf], 0,0,0);
    }
  }

#pragma unroll
  for (int nf=0;nf<4;nf++){
#pragma unroll
    for (int jp=0;jp<2;jp++){
      const int row0 = nf*16 + lk*4 + 2*jp;       // even
      if (row0 < 60){
        const unsigned nn = (unsigned)row0 / 10u;
        const int o = row0 - (int)nn*10;          // even, o+1 same node
        float att = outf[OFF_F + (nn*NB+b)*HW + pixb + lr];
        float f   = 2.f - att;
        float v0 = fmaxf(f*acc[nf][2*jp]   + pt[row0],   0.f);
        float v1 = fmaxf(f*acc[nf][2*jp+1] + pt[row0+1], 0.f);
        size_t idx = ((size_t)((nn*NB+b)*5 + (o>>1)))*HW + pixb + lr;
        unsigned old = wmsg_p[idx];
        float d0 = bf2f((unsigned short)(old & 0xffffu)) + v0;
        float d1 = bf2f((unsigned short)(old >> 16))     + v1;
        wmsg_p[idx] = pk2bf(d0, d1);
      }
    }
  }
}

// ---------------------------------------------------------------------------
// Kernel C: GRU gates conv (unchanged from round 15)
// ---------------------------------------------------------------------------
__global__ __launch_bounds__(256, 3)
void k_gru_gates(const float* __restrict__ pnn, const float* __restrict__ Wg,
                 const float* __restrict__ bg,
                 const unsigned* __restrict__ wmsg_p, unsigned* __restrict__ wrh_p,
                 unsigned* __restrict__ wu_p)
{
  __shared__ __align__(16) unsigned short tl[T6_N];
  __shared__ __align__(16) unsigned short wl[WG_ELEMS];
  const int bi = swz768(blockIdx.x);
  const int n  = bi >> 7;
  const int b  = (bi >> 5) & 3;
  const int y0 = (bi & 31) * 4;
  const int tid = threadIdx.x;

  const int base_nb  = (n*NB+b)*10;
  const int base_nb5 = (n*NB+b)*5;
  const float* pb = pnn + (size_t)base_nb*HW;

  short8_t zz = {0,0,0,0,0,0,0,0};
#pragma unroll
  for (int it=0; it<10; ++it){
    const int e = tid*8 + it*2048;
    if (e < T6_N) *reinterpret_cast<short8_t*>(&tl[e]) = zz;
  }
#pragma unroll
  for (int it=0; it<4; ++it){
    const int e = tid*8 + it*2048;
    if (e < WG_ELEMS) *reinterpret_cast<short8_t*>(&wl[e]) = zz;
  }
  __syncthreads();

  const float* Wn = Wg + n*3600;
#pragma unroll
  for (int it=0; it<8; ++it){
    const int e = tid + it*256;
    if (e < 1800){
      int sh = e/200, rem = e - sh*200, o = rem/10, chp = rem - o*10;
      float w0 = Wn[o*180 + (2*chp  )*9 + sh];
      float w1 = Wn[o*180 + (2*chp+1)*9 + sh];
      *reinterpret_cast<unsigned*>(&wl[(sh*32+o)*TCH + 2*chp]) = pk2bf(w0, w1);
    }
  }
#pragma unroll
  for (int it=0; it<30; ++it){
    const int e = tid + it*256;
    int row = e/1280, rem = e - row*1280, chp = rem>>7, x = rem&127;
    int yy = y0 - 1 + row;
    if ((unsigned)yy < 128u){
      unsigned pk;
      if (chp < 5){
        pk = wmsg_p[((size_t)(base_nb5 + chp))*HW + yy*WID + x];
      } else {
        const float* s0 = pb + (size_t)(2*chp-10)*HW;
        pk = pk2bf(s0[yy*WID + x], s0[HW + yy*WID + x]);
      }
      *reinterpret_cast<unsigned*>(&tl[(row*TROW + x+1)*TCH + 2*chp]) = pk;
    }
  }
  __syncthreads();

  const int l  = tid & 63;
  const int w  = tid >> 6;
  const int lr = l & 15;
  const int lk = l >> 4;

  short8_t wa0[9], wa1[9];
#pragma unroll
  for (int sh=0; sh<9; sh++){
    wa0[sh] = (lk<3) ? *reinterpret_cast<const short8_t*>(&wl[(sh*32 +      lr)*TCH + lk*8]) : zz;
    wa1[sh] = (lk<3) ? *reinterpret_cast<const short8_t*>(&wl[(sh*32 + 16 + lr)*TCH + lk*8]) : zz;
  }
  float bs0[4], bs1[4];
#pragma unroll
  for (int j=0;j<4;j++){
    int o = lk*4 + j;
    bs0[j] = bg[n*20 + o];
    int o1 = 16 + lk*4 + j;
    bs1[j] = (o1 < 20) ? bg[n*20 + o1] : 0.f;
  }

  for (int t=0; t<8; ++t){
    const int tile  = w*8 + t;
    const int row_t = tile >> 3;          // 0..3
    const int xloc  = (tile & 7) * 16;

    float4_t a0 = {0.f,0.f,0.f,0.f}, a1 = {0.f,0.f,0.f,0.f};
#pragma unroll
    for (int sh=0; sh<9; sh++){
      const int dy = sh/3, dx = sh - dy*3;
      const int addr = ((row_t + dy)*TROW + (xloc + lr + dx))*TCH + lk*8;
      short8_t bf = (lk<3) ? *reinterpret_cast<const short8_t*>(&tl[addr]) : zz;
      a0 = __builtin_amdgcn_mfma_f32_16x16x32_bf16(wa0[sh], bf, a0, 0,0,0);
      a1 = __builtin_amdgcn_mfma_f32_16x16x32_bf16(wa1[sh], bf, a1, 0,0,0);
    }

    const int pix = (y0 + row_t)*WID + xloc + lr;
#pragma unroll
    for (int jp=0; jp<2; ++jp){
      const int j0 = 2*jp;
      const int o  = lk*4 + j0;
      float g0 = sig_(a0[j0]   + bs0[j0]);
      float g1 = sig_(a0[j0+1] + bs0[j0+1]);
      if (o < 10){
        float h0 = pb[(size_t)o*HW + pix];
        float h1 = pb[(size_t)(o+1)*HW + pix];
        wrh_p[((size_t)(base_nb5 + (o>>1)))*HW + pix] = pk2bf(g0*h0, g1*h1);
      } else {
        wu_p[((size_t)(base_nb5 + ((o-10)>>1)))*HW + pix] = pk2bf(g0, g1);
      }
    }
    if (lk == 0){
#pragma unroll
      for (int jp=0; jp<2; ++jp){
        const int j0 = 2*jp;
        const int o1 = 16 + j0;                  // u ch 6..9
        float g0 = sig_(a1[j0]   + bs1[j0]);
        float g1 = sig_(a1[j0+1] + bs1[j0+1]);
        wu_p[((size_t)(base_nb5 + ((o1-10)>>1)))*HW + pix] = pk2bf(g0, g1);
      }
    }
  }
}

// ---------------------------------------------------------------------------
// Kernel D: candidate conv + GRU blend (unchanged from round 15)
// ---------------------------------------------------------------------------
__global__ __launch_bounds__(256, 3)
void k_gru_out(const float* __restrict__ pnn, const float* __restrict__ Wc,
               const float* __restrict__ bc,
               const unsigned* __restrict__ wmsg_p, const unsigned* __restrict__ wrh_p,
               const unsigned* __restrict__ wu_p, float* __restrict__ out)
{
  __shared__ __align__(16) unsigned short tl[T6_N];
  __shared__ __align__(16) unsigned short wl[WC_ELEMS];
  const int bi = swz768(blockIdx.x);
  const int n  = bi >> 7;
  const int b  = (bi >> 5) & 3;
  const int y0 = (bi & 31) * 4;
  const int tid = threadIdx.x;

  const int base_nb  = (n*NB+b)*10;
  const int base_nb5 = (n*NB+b)*5;
  const float* pb = pnn + (size_t)base_nb*HW;

  short8_t zz = {0,0,0,0,0,0,0,0};
#pragma unroll
  for (int it=0; it<10; ++it){
    const int e = tid*8 + it*2048;
    if (e < T6_N) *reinterpret_cast<short8_t*>(&tl[e]) = zz;
  }
#pragma unroll
  for (int it=0; it<2; ++it){
    const int e = tid*8 + it*2048;
    if (e < WC_ELEMS) *reinterpret_cast<short8_t*>(&wl[e]) = zz;
  }
  __syncthreads();

  const float* Wn = Wc + n*1800;
#pragma unroll
  for (int it=0; it<4; ++it){
    const int e = tid + it*256;
    if (e < 900){
      int sh = e/100, rem = e - sh*100, o = rem/10, chp = rem - o*10;
      float w0 = Wn[o*180 + (2*chp  )*9 + sh];
      float w1 = Wn[o*180 + (2*chp+1)*9 + sh];
      *reinterpret_cast<unsigned*>(&wl[(sh*16+o)*TCH + 2*chp]) = pk2bf(w0, w1);
    }
  }
#pragma unroll
  for (int it=0; it<30; ++it){
    const int e = tid + it*256;
    int row = e/1280, rem = e - row*1280, chp = rem>>7, x = rem&127;
    int yy = y0 - 1 + row;
    if ((unsigned)yy < 128u){
      unsigned pk;
      if (chp < 5){
        pk = wmsg_p[((size_t)(base_nb5 + chp))*HW + yy*WID + x];
      } else {
        pk = wrh_p[((size_t)(base_nb5 + (chp-5)))*HW + yy*WID + x];
      }
      *reinterpret_cast<unsigned*>(&tl[(row*TROW + x+1)*TCH + 2*chp]) = pk;
    }
  }
  __syncthreads();

  const int l  = tid & 63;
  const int w  = tid >> 6;
  const int lr = l & 15;
  const int lk = l >> 4;

  short8_t wa[9];
#pragma unroll
  for (int sh=0; sh<9; sh++)
    wa[sh] = (lk<3) ? *reinterpret_cast<const short8_t*>(&wl[(sh*16 + lr)*TCH + lk*8]) : zz;

  float bs[4];
#pragma unroll
  for (int j=0;j<4;j++){
    int o = lk*4 + j;
    bs[j] = (o < 10) ? bc[n*10 + o] : 0.f;
  }

  for (int t=0; t<8; ++t){
    const int tile  = w*8 + t;
    const int row_t = tile >> 3;
    const int xloc  = (tile & 7) * 16;

    float4_t a0 = {0.f,0.f,0.f,0.f};
#pragma unroll
    for (int sh=0; sh<9; sh++){
      const int dy = sh/3, dx = sh - dy*3;
      const int addr = ((row_t + dy)*TROW + (xloc + lr + dx))*TCH + lk*8;
      short8_t bf = (lk<3) ? *reinterpret_cast<const short8_t*>(&tl[addr]) : zz;
      a0 = __builtin_amdgcn_mfma_f32_16x16x32_bf16(wa[sh], bf, a0, 0,0,0);
    }

    const int pix = (y0 + row_t)*WID + xloc + lr;
#pragma unroll
    for (int jp=0; jp<2; ++jp){
      const int j0 = 2*jp;
      const int o  = lk*4 + j0;
      if (o < 10){
        unsigned up = wu_p[((size_t)(base_nb5 + (o>>1)))*HW + pix];
        float u0 = bf2f((unsigned short)(up & 0xffffu));
        float u1 = bf2f((unsigned short)(up >> 16));
        float h0 = pb[(size_t)o*HW + pix];
        float h1 = pb[(size_t)(o+1)*HW + pix];
        float c0 = tanh_(a0[j0]   + bs[j0]);
        float c1 = tanh_(a0[j0+1] + bs[j0+1]);
        out[(size_t)(base_nb+o  )*HW + pix] = (1.f-u0)*h0 + u0*c0;
        out[(size_t)(base_nb+o+1)*HW + pix] = (1.f-u1)*h1 + u1*c1;
      }
    }
  }
}

// ---------------------------------------------------------------------------
extern "C" void kernel_launch(void* const* d_in, const int* in_sizes, int n_in,
                              void* d_out, int out_size, void* d_ws, size_t ws_size,
                              hipStream_t stream)
{
  (void)in_sizes; (void)n_in; (void)out_size; (void)ws_size;
  const float* hn   = (const float*)d_in[1];
  const float* pnn  = (const float*)d_in[2];
  const float* xp   = (const float*)d_in[3];
  const float* Wdau = (const float*)d_in[4];
  const float* bdau = (const float*)d_in[5];
  const float* Wdal = (const float*)d_in[6];
  const float* bdal = (const float*)d_in[7];
  const float* Wd1  = (const float*)d_in[8];
  const float* s1v  = (const float*)d_in[9];
  const float* t1v  = (const float*)d_in[10];
  const float* Wd2  = (const float*)d_in[11];
  const float* s2v  = (const float*)d_in[12];
  const float* t2v  = (const float*)d_in[13];
  const float* Wa0  = (const float*)d_in[14];
  const float* Wa1  = (const float*)d_in[15];
  const float* Wa2  = (const float*)d_in[16];
  const float* Wa3  = (const float*)d_in[17];
  const float* Wa4  = (const float*)d_in[18];
  const float* Wa5  = (const float*)d_in[19];
  const float* batt = (const float*)d_in[20];
  const float* Wp   = (const float*)d_in[21];
  const float* ps   = (const float*)d_in[22];
  const float* pt   = (const float*)d_in[23];
  const float* Wg   = (const float*)d_in[24];
  const float* bg   = (const float*)d_in[25];
  const float* Wc   = (const float*)d_in[26];
  const float* bc   = (const float*)d_in[27];

  float* out = (float*)d_out;
  float* wsf = (float*)d_ws;
  unsigned* ws_msg = (unsigned*)wsf;                 // packed bf16 pairs [6*4*5*HW] u32
  unsigned* ws_rh  = (unsigned*)(wsf + 1966080);     // packed bf16 pairs [6*4*5*HW] u32
  unsigned* ws_u   = (unsigned*)(wsf + 3932160);     // packed bf16 pairs [6*4*5*HW] u32

  k_att_dec<<<dim3(1536), dim3(256), 0, stream>>>(hn, pnn, Wdau, bdau, Wdal, bdal,
      Wd1, s1v, t1v, Wd2, s2v, t2v, Wa0, Wa1, Wa2, Wa3, Wa4, Wa5, batt, out, ws_msg);
  k_proj<<<dim3(1024), dim3(256), 0, stream>>>(xp, Wp, ps, pt, (const float*)d_out, ws_msg);
  k_gru_gates<<<dim3(768), dim3(256), 0, stream>>>(pnn, Wg, bg, ws_msg, ws_rh, ws_u);
  k_gru_out<<<dim3(768), dim3(256), 0, stream>>>(pnn, Wc, bc, ws_msg, ws_rh, ws_u, out);
}